// Round 1
// baseline (3177.740 us; speedup 1.0000x reference)
//
#include <hip/hip_runtime.h>
#include <stdint.h>

#define DD 256
#define NNODE 60000
#define MPAD 60032            // 469 * 128
#define NEDGE 200000
#define NGRAPH 1500

typedef __bf16 bf16x8 __attribute__((ext_vector_type(8)));
typedef float f32x4 __attribute__((ext_vector_type(4)));

__device__ __forceinline__ unsigned short f2bf(float f) {
    union { float f; unsigned int u; } v; v.f = f;
    unsigned int r = v.u + 0x7FFFu + ((v.u >> 16) & 1u);
    return (unsigned short)(r >> 16);
}
__device__ __forceinline__ float bf2f(unsigned short h) {
    union { unsigned int u; float f; } v; v.u = ((unsigned int)h) << 16;
    return v.f;
}
__device__ __forceinline__ void gload_lds16(const void* g, void* l) {
    __builtin_amdgcn_global_load_lds((const __attribute__((address_space(1))) void*)g,
                                     (__attribute__((address_space(3))) void*)l, 16, 0, 0);
}

// ---------------- weight prep: transposed bf16 weights ----------------
// wc1[n*512+k] = bf16( k<256 ? W1[k][n] : W3[k-256][n] )   (W1=mlpW[0:256], W3=mlpW[512:768])
// wc2[n*512+k] = bf16( k<256 ? W2[k][n] : W3[k-256][n] ) = bf16( mlpW[(k+256)*256+n] )
// nnt[n*256+k] = bf16( nnW[k][n] )
__global__ __launch_bounds__(256) void prep_weights(const float* __restrict__ mlpW,
                                                    const float* __restrict__ nnW,
                                                    unsigned short* __restrict__ wc1,
                                                    unsigned short* __restrict__ wc2,
                                                    unsigned short* __restrict__ nnt) {
    int idx = blockIdx.x * 256 + threadIdx.x;
    if (idx < 256 * 512) {
        int n = idx >> 9, k = idx & 511;
        float v1 = (k < 256) ? mlpW[k * DD + n] : mlpW[(k + 256) * DD + n];
        wc1[idx] = f2bf(v1);
        wc2[idx] = f2bf(mlpW[(k + 256) * DD + n]);
    }
    if (idx < 256 * 256) {
        int n = idx >> 8, k = idx & 255;
        nnt[idx] = f2bf(nnW[k * DD + n]);
    }
}

// ---------------- u/v chains + BN fold ----------------
__global__ __launch_bounds__(256) void prep_uv(const float* __restrict__ eW, const float* __restrict__ eb,
                                               const float* __restrict__ mlpW, const float* __restrict__ mlpb,
                                               const float* __restrict__ nnb,
                                               const float* __restrict__ bn_g, const float* __restrict__ bn_b,
                                               const float* __restrict__ bn_m, const float* __restrict__ bn_v,
                                               float* __restrict__ u_all, float* __restrict__ v_all,
                                               float* __restrict__ scale, float* __restrict__ shift) {
    __shared__ float uc[DD], vc[DD];
    int d = threadIdx.x;
    uc[d] = eW[d];
    vc[d] = eb[d];
    float sc = bn_g[d] * rsqrtf(bn_v[d] + 1e-5f);
    scale[d] = sc;
    shift[d] = (nnb[d] - bn_m[d]) * sc + bn_b[d];
    __syncthreads();
    const float* W3 = mlpW + 2 * DD * DD;
    for (int it = 0; it < 4; ++it) {
        float su = 0.f, sv = 0.f;
        for (int k = 0; k < DD; ++k) {
            float w = W3[k * DD + d];
            su += uc[k] * w;
            sv += vc[k] * w;
        }
        sv += mlpb[d];
        u_all[it * DD + d] = su;
        v_all[it * DD + d] = sv;
        __syncthreads();
        uc[d] = su; vc[d] = sv;
        __syncthreads();
    }
}

// ---------------- x init: x = nf @ aW + ab  (K=92) ----------------
__global__ __launch_bounds__(256) void xinit(const float* __restrict__ nf, const float* __restrict__ aW,
                                             const float* __restrict__ ab, unsigned short* __restrict__ x) {
    __shared__ float nfs[32][93];
    int r0 = blockIdx.x * 32;
    int tid = threadIdx.x;
    for (int i = tid; i < 32 * 92; i += 256) {
        int r = i / 92, c = i - r * 92;
        int gr = r0 + r;
        nfs[r][c] = (gr < NNODE) ? nf[(size_t)gr * 92 + c] : 0.0f;
    }
    __syncthreads();
    float acc[32];
    float bias = ab[tid];
    #pragma unroll
    for (int r = 0; r < 32; ++r) acc[r] = bias;
    for (int k = 0; k < 92; ++k) {
        float w = aW[k * DD + tid];
        #pragma unroll
        for (int r = 0; r < 32; ++r) acc[r] += nfs[r][k] * w;
    }
    for (int r = 0; r < 32; ++r)
        x[(size_t)(r0 + r) * DD + tid] = f2bf(acc[r]);
}

// ---------------- GEMM: C[M x 256] = A[M x Ktot] * B^T, bf16 MFMA ----------------
// Tile: BM=128, BN=256(full), BK=64. 512 threads = 8 waves (2x4), each wave 64x64.
// EPI 0: Cout = C (P update, in-place safe: grid.y==1), aggOut = float(Xin)
// EPI 1: Cout = C (Q update)
// EPI 2: A is f32 (agg), staged with on-the-fly bf16 convert; Cout = relu(C*scale+shift)
template <int EPI>
__global__ __launch_bounds__(512) void gemm_kernel(
    const unsigned short* __restrict__ A0b, const float* __restrict__ A0f,
    const unsigned short* __restrict__ A1,
    const unsigned short* __restrict__ Bt, int btStride, int Ktot,
    const unsigned short* __restrict__ Xin,
    unsigned short* __restrict__ Cout, float* __restrict__ aggOut,
    const float* __restrict__ scale, const float* __restrict__ shift) {
    __shared__ unsigned short As[128][64];
    __shared__ unsigned short Bs[256][64];
    const int tid = threadIdx.x;
    const int lane = tid & 63, wid = tid >> 6;
    const int wr = wid >> 2, wc = wid & 3;
    const int m0 = blockIdx.x * 128;
    const int lr = lane & 15, lq = lane >> 4;
    const int srow = tid >> 3;        // 0..63
    const int scol = (tid & 7) * 8;   // element col, 0..56

    f32x4 acc[4][4];
    #pragma unroll
    for (int m = 0; m < 4; ++m)
        #pragma unroll
        for (int n = 0; n < 4; ++n) {
            f32x4 z = {0.f, 0.f, 0.f, 0.f};
            acc[m][n] = z;
        }

    const int nk = Ktot >> 6;
    for (int kt = 0; kt < nk; ++kt) {
        const int k0 = kt << 6;
        if (EPI == 2) {
            #pragma unroll
            for (int p = 0; p < 2; ++p) {
                int row = p * 64 + srow;
                const float* src = A0f + (size_t)(m0 + row) * DD + k0 + scol;
                float4 v0 = *(const float4*)(src);
                float4 v1 = *(const float4*)(src + 4);
                uint4 w;
                w.x = (unsigned)f2bf(v0.x) | ((unsigned)f2bf(v0.y) << 16);
                w.y = (unsigned)f2bf(v0.z) | ((unsigned)f2bf(v0.w) << 16);
                w.z = (unsigned)f2bf(v1.x) | ((unsigned)f2bf(v1.y) << 16);
                w.w = (unsigned)f2bf(v1.z) | ((unsigned)f2bf(v1.w) << 16);
                *(uint4*)(&As[row][scol]) = w;
            }
        } else {
            const unsigned short* Ap; int ka;
            if (k0 < 256) { Ap = A0b; ka = k0; } else { Ap = A1; ka = k0 - 256; }
            #pragma unroll
            for (int p = 0; p < 2; ++p) {
                int row = p * 64 + srow;
                gload_lds16(Ap + (size_t)(m0 + row) * DD + ka + scol, &As[row][scol]);
            }
        }
        #pragma unroll
        for (int p = 0; p < 4; ++p) {
            int row = p * 64 + srow;
            gload_lds16(Bt + (size_t)row * btStride + k0 + scol, &Bs[row][scol]);
        }
        __syncthreads();
        #pragma unroll
        for (int h = 0; h < 2; ++h) {
            bf16x8 af[4], bfr[4];
            #pragma unroll
            for (int m = 0; m < 4; ++m)
                af[m] = *reinterpret_cast<const bf16x8*>(&As[wr * 64 + m * 16 + lr][h * 32 + lq * 8]);
            #pragma unroll
            for (int n = 0; n < 4; ++n)
                bfr[n] = *reinterpret_cast<const bf16x8*>(&Bs[wc * 64 + n * 16 + lr][h * 32 + lq * 8]);
            #pragma unroll
            for (int m = 0; m < 4; ++m)
                #pragma unroll
                for (int n = 0; n < 4; ++n)
                    acc[m][n] = __builtin_amdgcn_mfma_f32_16x16x32_bf16(af[m], bfr[n], acc[m][n], 0, 0, 0);
        }
        __syncthreads();
    }

    #pragma unroll
    for (int m = 0; m < 4; ++m) {
        const int rb = m0 + wr * 64 + m * 16 + lq * 4;
        #pragma unroll
        for (int n = 0; n < 4; ++n) {
            const int c = wc * 64 + n * 16 + lr;
            #pragma unroll
            for (int j = 0; j < 4; ++j) {
                const size_t idx = (size_t)(rb + j) * DD + c;
                float cv = acc[m][n][j];
                if (EPI == 0) {
                    float xf = bf2f(Xin[idx]);
                    Cout[idx] = f2bf(cv);
                    aggOut[idx] = xf;
                } else if (EPI == 1) {
                    Cout[idx] = f2bf(cv);
                } else {
                    float y = fmaxf(cv * scale[c] + shift[c], 0.f);
                    Cout[idx] = f2bf(y);
                }
            }
        }
    }
}

// ---------------- edge pass: agg[col] += relu(x[row]+P[row]+Q[col]+aw*u+v) ----------------
__global__ __launch_bounds__(256) void edge_kernel(const int* __restrict__ ei, const float* __restrict__ aw,
                                                   const unsigned short* __restrict__ X,
                                                   const unsigned short* __restrict__ P,
                                                   const unsigned short* __restrict__ Q,
                                                   const float* __restrict__ u, const float* __restrict__ v,
                                                   float* __restrict__ agg) {
    const int lane = threadIdx.x & 63, wid = threadIdx.x >> 6;
    const int e = blockIdx.x * 4 + wid;
    const int r = ei[e], c = ei[NEDGE + e];
    const float w = aw[e];
    ushort4 xv = ((const ushort4*)X)[(size_t)r * 64 + lane];
    ushort4 pv = ((const ushort4*)P)[(size_t)r * 64 + lane];
    ushort4 qv = ((const ushort4*)Q)[(size_t)c * 64 + lane];
    float4 uu = ((const float4*)u)[lane];
    float4 vv = ((const float4*)v)[lane];
    float t0 = bf2f(xv.x) + bf2f(pv.x) + bf2f(qv.x) + w * uu.x + vv.x;
    float t1 = bf2f(xv.y) + bf2f(pv.y) + bf2f(qv.y) + w * uu.y + vv.y;
    float t2 = bf2f(xv.z) + bf2f(pv.z) + bf2f(qv.z) + w * uu.z + vv.z;
    float t3 = bf2f(xv.w) + bf2f(pv.w) + bf2f(qv.w) + w * uu.w + vv.w;
    float* ap = agg + (size_t)c * DD + lane * 4;
    unsafeAtomicAdd(ap + 0, fmaxf(t0, 0.f));
    unsafeAtomicAdd(ap + 1, fmaxf(t1, 0.f));
    unsafeAtomicAdd(ap + 2, fmaxf(t2, 0.f));
    unsafeAtomicAdd(ap + 3, fmaxf(t3, 0.f));
}

// ---------------- pooling: pooled[batch[n]] += x[n], batch sorted ----------------
__global__ __launch_bounds__(256) void pool_kernel(const unsigned short* __restrict__ x,
                                                   const int* __restrict__ batch,
                                                   float* __restrict__ pooled) {
    const int lane = threadIdx.x & 63, wid = threadIdx.x >> 6;
    const int base = (blockIdx.x * 4 + wid) * 8;
    float4 acc = make_float4(0.f, 0.f, 0.f, 0.f);
    int gcur = -1;
    for (int i = 0; i < 8; ++i) {
        int n = base + i;
        if (n >= NNODE) break;
        int g = batch[n];
        if (g != gcur) {
            if (gcur >= 0) {
                float* pp = pooled + (size_t)gcur * DD + lane * 4;
                unsafeAtomicAdd(pp + 0, acc.x);
                unsafeAtomicAdd(pp + 1, acc.y);
                unsafeAtomicAdd(pp + 2, acc.z);
                unsafeAtomicAdd(pp + 3, acc.w);
            }
            gcur = g;
            acc = make_float4(0.f, 0.f, 0.f, 0.f);
        }
        ushort4 xv = ((const ushort4*)x)[(size_t)n * 64 + lane];
        acc.x += bf2f(xv.x); acc.y += bf2f(xv.y);
        acc.z += bf2f(xv.z); acc.w += bf2f(xv.w);
    }
    if (gcur >= 0) {
        float* pp = pooled + (size_t)gcur * DD + lane * 4;
        unsafeAtomicAdd(pp + 0, acc.x);
        unsafeAtomicAdd(pp + 1, acc.y);
        unsafeAtomicAdd(pp + 2, acc.z);
        unsafeAtomicAdd(pp + 3, acc.w);
    }
}

// ---------------- out: d_out = pooled @ outW + outb ----------------
__global__ __launch_bounds__(64) void out_kernel(const float* __restrict__ pooled,
                                                 const float* __restrict__ outW,
                                                 const float* __restrict__ outb,
                                                 float* __restrict__ out) {
    const int g = blockIdx.x, lane = threadIdx.x;
    float4 p = ((const float4*)pooled)[g * 64 + lane];
    float s[6];
    #pragma unroll
    for (int j = 0; j < 6; ++j) {
        float a = p.x * outW[(lane * 4 + 0) * 6 + j] + p.y * outW[(lane * 4 + 1) * 6 + j] +
                  p.z * outW[(lane * 4 + 2) * 6 + j] + p.w * outW[(lane * 4 + 3) * 6 + j];
        #pragma unroll
        for (int off = 32; off; off >>= 1) a += __shfl_down(a, off);
        s[j] = a;
    }
    if (lane == 0) {
        #pragma unroll
        for (int j = 0; j < 6; ++j) out[g * 6 + j] = s[j] + outb[j];
    }
}

extern "C" void kernel_launch(void* const* d_in, const int* in_sizes, int n_in,
                              void* d_out, int out_size, void* d_ws, size_t ws_size,
                              hipStream_t stream) {
    const float* nf    = (const float*)d_in[0];
    const int*   ei    = (const int*)d_in[1];
    const float* aw    = (const float*)d_in[2];
    const int*   batch = (const int*)d_in[3];
    const float* aW    = (const float*)d_in[4];
    const float* ab    = (const float*)d_in[5];
    const float* eW    = (const float*)d_in[6];
    const float* eb    = (const float*)d_in[7];
    const float* mlpW  = (const float*)d_in[8];
    const float* mlpb  = (const float*)d_in[9];
    const float* nnW   = (const float*)d_in[10];
    const float* nnb   = (const float*)d_in[11];
    const float* bn_g  = (const float*)d_in[12];
    const float* bn_b  = (const float*)d_in[13];
    const float* bn_m  = (const float*)d_in[14];
    const float* bn_v  = (const float*)d_in[15];
    const float* outW  = (const float*)d_in[16];
    const float* outb  = (const float*)d_in[17];
    float* out = (float*)d_out;

    char* ws = (char*)d_ws;
    size_t off = 0;
    auto alloc = [&](size_t bytes) -> void* {
        void* p = ws + off;
        off += (bytes + 255) & ~(size_t)255;
        return p;
    };
    unsigned short* x   = (unsigned short*)alloc((size_t)MPAD * DD * 2);
    unsigned short* P   = (unsigned short*)alloc((size_t)MPAD * DD * 2);
    unsigned short* Q   = (unsigned short*)alloc((size_t)MPAD * DD * 2);
    float*          agg = (float*)alloc((size_t)MPAD * DD * 4);
    unsigned short* wc1 = (unsigned short*)alloc(256 * 512 * 2);
    unsigned short* wc2 = (unsigned short*)alloc(256 * 512 * 2);
    unsigned short* nnt = (unsigned short*)alloc(256 * 256 * 2);
    float* u_all = (float*)alloc(4 * DD * 4);
    float* v_all = (float*)alloc(4 * DD * 4);
    float* scale = (float*)alloc(DD * 4);
    float* shift = (float*)alloc(DD * 4);
    float* pooled = (float*)alloc((size_t)NGRAPH * DD * 4);
    (void)ws_size; (void)in_sizes; (void)n_in; (void)out_size;

    prep_weights<<<512, 256, 0, stream>>>(mlpW, nnW, wc1, wc2, nnt);
    prep_uv<<<1, 256, 0, stream>>>(eW, eb, mlpW, mlpb, nnb, bn_g, bn_b, bn_m, bn_v,
                                   u_all, v_all, scale, shift);
    xinit<<<MPAD / 32, 256, 0, stream>>>(nf, aW, ab, x);

    for (int k = 0; k < 4; ++k) {
        int Ktot = k ? 512 : 256;
        gemm_kernel<0><<<MPAD / 128, 512, 0, stream>>>(x, nullptr, k ? P : nullptr, wc1, 512, Ktot,
                                                       x, P, agg, nullptr, nullptr);
        gemm_kernel<1><<<MPAD / 128, 512, 0, stream>>>(x, nullptr, k ? Q : nullptr, wc2, 512, Ktot,
                                                       nullptr, Q, nullptr, nullptr, nullptr);
        edge_kernel<<<NEDGE / 4, 256, 0, stream>>>(ei, aw, x, P, Q, u_all + k * DD, v_all + k * DD, agg);
        gemm_kernel<2><<<MPAD / 128, 512, 0, stream>>>(nullptr, agg, nullptr, nnt, 256, 256,
                                                       nullptr, x, nullptr, scale, shift);
    }

    hipMemsetAsync(pooled, 0, (size_t)NGRAPH * DD * 4, stream);
    pool_kernel<<<(NNODE + 31) / 32, 256, 0, stream>>>(x, batch, pooled);
    out_kernel<<<NGRAPH, 64, 0, stream>>>(pooled, outW, outb, out);
}

// Round 2
// 653.918 us; speedup vs baseline: 4.8595x; 4.8595x over previous
//
#include <hip/hip_runtime.h>
#include <stdint.h>

#define DD 256
#define NNODE 60000
#define MPAD 60032            // 469 * 128
#define NEDGE 200000
#define NGRAPH 1500
#define NCHUNK 59             // ceil(60000/1024)

typedef __bf16 bf16x8 __attribute__((ext_vector_type(8)));
typedef float f32x4 __attribute__((ext_vector_type(4)));

__device__ __forceinline__ unsigned short f2bf(float f) {
    union { float f; unsigned int u; } v; v.f = f;
    unsigned int r = v.u + 0x7FFFu + ((v.u >> 16) & 1u);
    return (unsigned short)(r >> 16);
}
__device__ __forceinline__ float bf2f(unsigned short h) {
    union { unsigned int u; float f; } v; v.u = ((unsigned int)h) << 16;
    return v.f;
}
__device__ __forceinline__ void gload_lds16(const void* g, void* l) {
    __builtin_amdgcn_global_load_lds((const __attribute__((address_space(1))) void*)g,
                                     (__attribute__((address_space(3))) void*)l, 16, 0, 0);
}

// ---------------- weight prep: transposed bf16 weights ----------------
__global__ __launch_bounds__(256) void prep_weights(const float* __restrict__ mlpW,
                                                    const float* __restrict__ nnW,
                                                    unsigned short* __restrict__ wc1,
                                                    unsigned short* __restrict__ wc2,
                                                    unsigned short* __restrict__ nnt) {
    int idx = blockIdx.x * 256 + threadIdx.x;
    if (idx < 256 * 512) {
        int n = idx >> 9, k = idx & 511;
        float v1 = (k < 256) ? mlpW[k * DD + n] : mlpW[(k + 256) * DD + n];
        wc1[idx] = f2bf(v1);
        wc2[idx] = f2bf(mlpW[(k + 256) * DD + n]);
    }
    if (idx < 256 * 256) {
        int n = idx >> 8, k = idx & 255;
        nnt[idx] = f2bf(nnW[k * DD + n]);
    }
}

// ---------------- u/v chains + BN fold ----------------
__global__ __launch_bounds__(256) void prep_uv(const float* __restrict__ eW, const float* __restrict__ eb,
                                               const float* __restrict__ mlpW, const float* __restrict__ mlpb,
                                               const float* __restrict__ nnb,
                                               const float* __restrict__ bn_g, const float* __restrict__ bn_b,
                                               const float* __restrict__ bn_m, const float* __restrict__ bn_v,
                                               float* __restrict__ u_all, float* __restrict__ v_all,
                                               float* __restrict__ scale, float* __restrict__ shift) {
    __shared__ float uc[DD], vc[DD];
    int d = threadIdx.x;
    uc[d] = eW[d];
    vc[d] = eb[d];
    float sc = bn_g[d] * rsqrtf(bn_v[d] + 1e-5f);
    scale[d] = sc;
    shift[d] = (nnb[d] - bn_m[d]) * sc + bn_b[d];
    __syncthreads();
    const float* W3 = mlpW + 2 * DD * DD;
    for (int it = 0; it < 4; ++it) {
        float su = 0.f, sv = 0.f;
        for (int k = 0; k < DD; ++k) {
            float w = W3[k * DD + d];
            su += uc[k] * w;
            sv += vc[k] * w;
        }
        sv += mlpb[d];
        u_all[it * DD + d] = su;
        v_all[it * DD + d] = sv;
        __syncthreads();
        uc[d] = su; vc[d] = sv;
        __syncthreads();
    }
}

// ---------------- x init: x = nf @ aW + ab  (K=92) ----------------
__global__ __launch_bounds__(256) void xinit(const float* __restrict__ nf, const float* __restrict__ aW,
                                             const float* __restrict__ ab, unsigned short* __restrict__ x) {
    __shared__ float nfs[32][93];
    int r0 = blockIdx.x * 32;
    int tid = threadIdx.x;
    for (int i = tid; i < 32 * 92; i += 256) {
        int r = i / 92, c = i - r * 92;
        int gr = r0 + r;
        nfs[r][c] = (gr < NNODE) ? nf[(size_t)gr * 92 + c] : 0.0f;
    }
    __syncthreads();
    float acc[32];
    float bias = ab[tid];
    #pragma unroll
    for (int r = 0; r < 32; ++r) acc[r] = bias;
    for (int k = 0; k < 92; ++k) {
        float w = aW[k * DD + tid];
        #pragma unroll
        for (int r = 0; r < 32; ++r) acc[r] += nfs[r][k] * w;
    }
    for (int r = 0; r < 32; ++r)
        x[(size_t)(r0 + r) * DD + tid] = f2bf(acc[r]);
}

// ---------------- CSR build ----------------
__global__ __launch_bounds__(256) void hist_kernel(const int* __restrict__ ei, int* __restrict__ counts) {
    int e = blockIdx.x * 256 + threadIdx.x;
    if (e < NEDGE) atomicAdd(&counts[ei[NEDGE + e]], 1);
}

__global__ __launch_bounds__(256) void scan1(const int* __restrict__ counts, int* __restrict__ blockSums) {
    int t = threadIdx.x;
    int base = blockIdx.x * 1024 + t * 4;
    int s = 0;
    #pragma unroll
    for (int i = 0; i < 4; ++i) { int idx = base + i; if (idx < NNODE) s += counts[idx]; }
    __shared__ int red[256];
    red[t] = s; __syncthreads();
    for (int d = 128; d; d >>= 1) { if (t < d) red[t] += red[t + d]; __syncthreads(); }
    if (t == 0) blockSums[blockIdx.x] = red[0];
}

__global__ __launch_bounds__(64) void scan2(int* __restrict__ blockSums) {
    int t = threadIdx.x;
    int v = (t < NCHUNK) ? blockSums[t] : 0;
    int orig = v;
    #pragma unroll
    for (int d = 1; d < 64; d <<= 1) {
        int o = __shfl_up(v, d);
        if (t >= d) v += o;
    }
    if (t < NCHUNK) blockSums[t] = v - orig;   // exclusive
}

__global__ __launch_bounds__(256) void scan3(const int* __restrict__ counts, const int* __restrict__ blockSums,
                                             int* __restrict__ offsets, int* __restrict__ cursor) {
    int t = threadIdx.x;
    int base = blockIdx.x * 1024 + t * 4;
    int c[4]; int s = 0;
    #pragma unroll
    for (int i = 0; i < 4; ++i) { int idx = base + i; c[i] = (idx < NNODE) ? counts[idx] : 0; s += c[i]; }
    __shared__ int lds[256];
    lds[t] = s; __syncthreads();
    for (int d = 1; d < 256; d <<= 1) {
        int v = (t >= d) ? lds[t - d] : 0;
        __syncthreads();
        lds[t] += v;
        __syncthreads();
    }
    int off = blockSums[blockIdx.x] + lds[t] - s;
    #pragma unroll
    for (int i = 0; i < 4; ++i) {
        int idx = base + i;
        if (idx < NNODE) { offsets[idx] = off; cursor[idx] = off; off += c[i]; }
    }
}

__global__ __launch_bounds__(256) void scatter_kernel(const int* __restrict__ ei, const float* __restrict__ aw,
                                                      int* __restrict__ cursor,
                                                      int* __restrict__ srow, float* __restrict__ sw) {
    int e = blockIdx.x * 256 + threadIdx.x;
    if (e < NEDGE) {
        int c = ei[NEDGE + e];
        int pos = atomicAdd(&cursor[c], 1);
        srow[pos] = ei[e];
        sw[pos] = aw[e];
    }
}

// ---------------- GEMM: C[M x 256] = A[M x Ktot] * B^T, bf16 MFMA ----------------
// EPI 1: Cout = C plain bf16 store (P / Q update; in-place over A1 is safe: block
//        reads only its own 128 A-rows before writing them)
// EPI 2: A is f32 (agg), staged with on-the-fly bf16 convert; Cout = relu(C*scale+shift)
template <int EPI>
__global__ __launch_bounds__(512) void gemm_kernel(
    const unsigned short* __restrict__ A0b, const float* __restrict__ A0f,
    const unsigned short* __restrict__ A1,
    const unsigned short* __restrict__ Bt, int btStride, int Ktot,
    unsigned short* __restrict__ Cout,
    const float* __restrict__ scale, const float* __restrict__ shift) {
    __shared__ unsigned short As[128][64];
    __shared__ unsigned short Bs[256][64];
    const int tid = threadIdx.x;
    const int lane = tid & 63, wid = tid >> 6;
    const int wr = wid >> 2, wc = wid & 3;
    const int m0 = blockIdx.x * 128;
    const int lr = lane & 15, lq = lane >> 4;
    const int srow = tid >> 3;        // 0..63
    const int scol = (tid & 7) * 8;   // element col, 0..56

    f32x4 acc[4][4];
    #pragma unroll
    for (int m = 0; m < 4; ++m)
        #pragma unroll
        for (int n = 0; n < 4; ++n) {
            f32x4 z = {0.f, 0.f, 0.f, 0.f};
            acc[m][n] = z;
        }

    const int nk = Ktot >> 6;
    for (int kt = 0; kt < nk; ++kt) {
        const int k0 = kt << 6;
        if (EPI == 2) {
            #pragma unroll
            for (int p = 0; p < 2; ++p) {
                int row = p * 64 + srow;
                const float* src = A0f + (size_t)(m0 + row) * DD + k0 + scol;
                float4 v0 = *(const float4*)(src);
                float4 v1 = *(const float4*)(src + 4);
                uint4 w;
                w.x = (unsigned)f2bf(v0.x) | ((unsigned)f2bf(v0.y) << 16);
                w.y = (unsigned)f2bf(v0.z) | ((unsigned)f2bf(v0.w) << 16);
                w.z = (unsigned)f2bf(v1.x) | ((unsigned)f2bf(v1.y) << 16);
                w.w = (unsigned)f2bf(v1.z) | ((unsigned)f2bf(v1.w) << 16);
                *(uint4*)(&As[row][scol]) = w;
            }
        } else {
            const unsigned short* Ap; int ka;
            if (k0 < 256) { Ap = A0b; ka = k0; } else { Ap = A1; ka = k0 - 256; }
            #pragma unroll
            for (int p = 0; p < 2; ++p) {
                int row = p * 64 + srow;
                gload_lds16(Ap + (size_t)(m0 + row) * DD + ka + scol, &As[row][scol]);
            }
        }
        #pragma unroll
        for (int p = 0; p < 4; ++p) {
            int row = p * 64 + srow;
            gload_lds16(Bt + (size_t)row * btStride + k0 + scol, &Bs[row][scol]);
        }
        __syncthreads();
        #pragma unroll
        for (int h = 0; h < 2; ++h) {
            bf16x8 af[4], bfr[4];
            #pragma unroll
            for (int m = 0; m < 4; ++m)
                af[m] = *reinterpret_cast<const bf16x8*>(&As[wr * 64 + m * 16 + lr][h * 32 + lq * 8]);
            #pragma unroll
            for (int n = 0; n < 4; ++n)
                bfr[n] = *reinterpret_cast<const bf16x8*>(&Bs[wc * 64 + n * 16 + lr][h * 32 + lq * 8]);
            #pragma unroll
            for (int m = 0; m < 4; ++m)
                #pragma unroll
                for (int n = 0; n < 4; ++n)
                    acc[m][n] = __builtin_amdgcn_mfma_f32_16x16x32_bf16(af[m], bfr[n], acc[m][n], 0, 0, 0);
        }
        __syncthreads();
    }

    #pragma unroll
    for (int m = 0; m < 4; ++m) {
        const int rb = m0 + wr * 64 + m * 16 + lq * 4;
        #pragma unroll
        for (int n = 0; n < 4; ++n) {
            const int c = wc * 64 + n * 16 + lr;
            #pragma unroll
            for (int j = 0; j < 4; ++j) {
                const size_t idx = (size_t)(rb + j) * DD + c;
                float cv = acc[m][n][j];
                if (EPI == 1) {
                    Cout[idx] = f2bf(cv);
                } else {
                    float y = fmaxf(cv * scale[c] + shift[c], 0.f);
                    Cout[idx] = f2bf(y);
                }
            }
        }
    }
}

// ---------------- edge pass (CSR gather): one wave per destination node ----------------
// agg[n] = x[n] + sum_{e: col(e)=n} relu( x[r]+P[r] + Q[n] + w*u + v )
__global__ __launch_bounds__(256) void edge_csr(const int* __restrict__ offsets, const int* __restrict__ counts,
                                                const int* __restrict__ srow, const float* __restrict__ sw,
                                                const unsigned short* __restrict__ X,
                                                const unsigned short* __restrict__ P,
                                                const unsigned short* __restrict__ Q,
                                                const float* __restrict__ u, const float* __restrict__ v,
                                                float* __restrict__ agg) {
    const int lane = threadIdx.x & 63, wid = threadIdx.x >> 6;
    const int n = blockIdx.x * 4 + wid;
    if (n >= NNODE) return;
    const int start = offsets[n];
    const int deg = counts[n];

    const ushort4* X4 = (const ushort4*)X;
    const ushort4* P4 = (const ushort4*)P;

    float4 uu = ((const float4*)u)[lane];
    float4 vv = ((const float4*)v)[lane];
    ushort4 qv = ((const ushort4*)Q)[(size_t)n * 64 + lane];
    // fold Q[n] + v into one base term
    const float qb0 = bf2f(qv.x) + vv.x;
    const float qb1 = bf2f(qv.y) + vv.y;
    const float qb2 = bf2f(qv.z) + vv.z;
    const float qb3 = bf2f(qv.w) + vv.w;

    ushort4 xv = X4[(size_t)n * 64 + lane];
    float a0 = bf2f(xv.x), a1 = bf2f(xv.y), a2 = bf2f(xv.z), a3 = bf2f(xv.w);

    for (int base = 0; base < deg; base += 64) {
        int m = deg - base; if (m > 64) m = 64;
        int myr = 0; float myw = 0.f;
        if (lane < m) { myr = srow[start + base + lane]; myw = sw[start + base + lane]; }
        for (int i = 0; i < m; ++i) {
            int r = __shfl(myr, i);
            float w = __shfl(myw, i);
            ushort4 x2 = X4[(size_t)r * 64 + lane];
            ushort4 p2 = P4[(size_t)r * 64 + lane];
            a0 += fmaxf(bf2f(x2.x) + bf2f(p2.x) + qb0 + w * uu.x, 0.f);
            a1 += fmaxf(bf2f(x2.y) + bf2f(p2.y) + qb1 + w * uu.y, 0.f);
            a2 += fmaxf(bf2f(x2.z) + bf2f(p2.z) + qb2 + w * uu.z, 0.f);
            a3 += fmaxf(bf2f(x2.w) + bf2f(p2.w) + qb3 + w * uu.w, 0.f);
        }
    }
    float4 o; o.x = a0; o.y = a1; o.z = a2; o.w = a3;
    ((float4*)agg)[(size_t)n * 64 + lane] = o;
}

// ---------------- pooling: pooled[batch[n]] += x[n], batch sorted ----------------
__global__ __launch_bounds__(256) void pool_kernel(const unsigned short* __restrict__ x,
                                                   const int* __restrict__ batch,
                                                   float* __restrict__ pooled) {
    const int lane = threadIdx.x & 63, wid = threadIdx.x >> 6;
    const int base = (blockIdx.x * 4 + wid) * 8;
    float4 acc = make_float4(0.f, 0.f, 0.f, 0.f);
    int gcur = -1;
    for (int i = 0; i < 8; ++i) {
        int n = base + i;
        if (n >= NNODE) break;
        int g = batch[n];
        if (g != gcur) {
            if (gcur >= 0) {
                float* pp = pooled + (size_t)gcur * DD + lane * 4;
                unsafeAtomicAdd(pp + 0, acc.x);
                unsafeAtomicAdd(pp + 1, acc.y);
                unsafeAtomicAdd(pp + 2, acc.z);
                unsafeAtomicAdd(pp + 3, acc.w);
            }
            gcur = g;
            acc = make_float4(0.f, 0.f, 0.f, 0.f);
        }
        ushort4 xv = ((const ushort4*)x)[(size_t)n * 64 + lane];
        acc.x += bf2f(xv.x); acc.y += bf2f(xv.y);
        acc.z += bf2f(xv.z); acc.w += bf2f(xv.w);
    }
    if (gcur >= 0) {
        float* pp = pooled + (size_t)gcur * DD + lane * 4;
        unsafeAtomicAdd(pp + 0, acc.x);
        unsafeAtomicAdd(pp + 1, acc.y);
        unsafeAtomicAdd(pp + 2, acc.z);
        unsafeAtomicAdd(pp + 3, acc.w);
    }
}

// ---------------- out: d_out = pooled @ outW + outb ----------------
__global__ __launch_bounds__(64) void out_kernel(const float* __restrict__ pooled,
                                                 const float* __restrict__ outW,
                                                 const float* __restrict__ outb,
                                                 float* __restrict__ out) {
    const int g = blockIdx.x, lane = threadIdx.x;
    float4 p = ((const float4*)pooled)[g * 64 + lane];
    float s[6];
    #pragma unroll
    for (int j = 0; j < 6; ++j) {
        float a = p.x * outW[(lane * 4 + 0) * 6 + j] + p.y * outW[(lane * 4 + 1) * 6 + j] +
                  p.z * outW[(lane * 4 + 2) * 6 + j] + p.w * outW[(lane * 4 + 3) * 6 + j];
        #pragma unroll
        for (int off = 32; off; off >>= 1) a += __shfl_down(a, off);
        s[j] = a;
    }
    if (lane == 0) {
        #pragma unroll
        for (int j = 0; j < 6; ++j) out[g * 6 + j] = s[j] + outb[j];
    }
}

extern "C" void kernel_launch(void* const* d_in, const int* in_sizes, int n_in,
                              void* d_out, int out_size, void* d_ws, size_t ws_size,
                              hipStream_t stream) {
    const float* nf    = (const float*)d_in[0];
    const int*   ei    = (const int*)d_in[1];
    const float* aw    = (const float*)d_in[2];
    const int*   batch = (const int*)d_in[3];
    const float* aW    = (const float*)d_in[4];
    const float* ab    = (const float*)d_in[5];
    const float* eW    = (const float*)d_in[6];
    const float* eb    = (const float*)d_in[7];
    const float* mlpW  = (const float*)d_in[8];
    const float* mlpb  = (const float*)d_in[9];
    const float* nnW   = (const float*)d_in[10];
    const float* nnb   = (const float*)d_in[11];
    const float* bn_g  = (const float*)d_in[12];
    const float* bn_b  = (const float*)d_in[13];
    const float* bn_m  = (const float*)d_in[14];
    const float* bn_v  = (const float*)d_in[15];
    const float* outW  = (const float*)d_in[16];
    const float* outb  = (const float*)d_in[17];
    float* out = (float*)d_out;

    char* ws = (char*)d_ws;
    size_t off = 0;
    auto alloc = [&](size_t bytes) -> void* {
        void* p = ws + off;
        off += (bytes + 255) & ~(size_t)255;
        return p;
    };
    unsigned short* x   = (unsigned short*)alloc((size_t)MPAD * DD * 2);
    unsigned short* P   = (unsigned short*)alloc((size_t)MPAD * DD * 2);
    unsigned short* Q   = (unsigned short*)alloc((size_t)MPAD * DD * 2);
    float*          agg = (float*)alloc((size_t)MPAD * DD * 4);
    unsigned short* wc1 = (unsigned short*)alloc(256 * 512 * 2);
    unsigned short* wc2 = (unsigned short*)alloc(256 * 512 * 2);
    unsigned short* nnt = (unsigned short*)alloc(256 * 256 * 2);
    float* u_all = (float*)alloc(4 * DD * 4);
    float* v_all = (float*)alloc(4 * DD * 4);
    float* scale = (float*)alloc(DD * 4);
    float* shift = (float*)alloc(DD * 4);
    float* pooled = (float*)alloc((size_t)NGRAPH * DD * 4);
    int* counts  = (int*)alloc((size_t)NNODE * 4);
    int* offsets = (int*)alloc((size_t)NNODE * 4);
    int* cursor  = (int*)alloc((size_t)NNODE * 4);
    int* blockSums = (int*)alloc(NCHUNK * 4);
    int* srowB   = (int*)alloc((size_t)NEDGE * 4);
    float* swB   = (float*)alloc((size_t)NEDGE * 4);
    (void)ws_size; (void)in_sizes; (void)n_in; (void)out_size;

    // one-time prep
    prep_weights<<<512, 256, 0, stream>>>(mlpW, nnW, wc1, wc2, nnt);
    prep_uv<<<1, 256, 0, stream>>>(eW, eb, mlpW, mlpb, nnb, bn_g, bn_b, bn_m, bn_v,
                                   u_all, v_all, scale, shift);
    xinit<<<MPAD / 32, 256, 0, stream>>>(nf, aW, ab, x);

    // CSR build (once; shared by all 4 layers)
    hipMemsetAsync(counts, 0, (size_t)NNODE * 4, stream);
    hist_kernel<<<(NEDGE + 255) / 256, 256, 0, stream>>>(ei, counts);
    scan1<<<NCHUNK, 256, 0, stream>>>(counts, blockSums);
    scan2<<<1, 64, 0, stream>>>(blockSums);
    scan3<<<NCHUNK, 256, 0, stream>>>(counts, blockSums, offsets, cursor);
    scatter_kernel<<<(NEDGE + 255) / 256, 256, 0, stream>>>(ei, aw, cursor, srowB, swB);

    for (int k = 0; k < 4; ++k) {
        int Ktot = k ? 512 : 256;
        gemm_kernel<1><<<MPAD / 128, 512, 0, stream>>>(x, nullptr, k ? P : nullptr, wc1, 512, Ktot,
                                                       P, nullptr, nullptr);
        gemm_kernel<1><<<MPAD / 128, 512, 0, stream>>>(x, nullptr, k ? Q : nullptr, wc2, 512, Ktot,
                                                       Q, nullptr, nullptr);
        edge_csr<<<(NNODE + 3) / 4, 256, 0, stream>>>(offsets, counts, srowB, swB, x, P, Q,
                                                      u_all + k * DD, v_all + k * DD, agg);
        gemm_kernel<2><<<MPAD / 128, 512, 0, stream>>>(nullptr, agg, nullptr, nnt, 256, 256,
                                                       x, scale, shift);
    }

    hipMemsetAsync(pooled, 0, (size_t)NGRAPH * DD * 4, stream);
    pool_kernel<<<(NNODE + 31) / 32, 256, 0, stream>>>(x, batch, pooled);
    out_kernel<<<NGRAPH, 64, 0, stream>>>(pooled, outW, outb, out);
}

// Round 3
// 620.360 us; speedup vs baseline: 5.1224x; 1.0541x over previous
//
#include <hip/hip_runtime.h>
#include <stdint.h>

#define DD 256
#define NNODE 60000
#define MPAD 60032            // 469 * 128
#define NEDGE 200000
#define NGRAPH 1500
#define NCHUNK 59             // ceil(60000/1024)

typedef __bf16 bf16x8 __attribute__((ext_vector_type(8)));
typedef float f32x4 __attribute__((ext_vector_type(4)));
typedef unsigned short us8 __attribute__((ext_vector_type(8)));

__device__ __forceinline__ unsigned short f2bf(float f) {
    union { float f; unsigned int u; } v; v.f = f;
    unsigned int r = v.u + 0x7FFFu + ((v.u >> 16) & 1u);
    return (unsigned short)(r >> 16);
}
__device__ __forceinline__ float bf2f(unsigned short h) {
    union { unsigned int u; float f; } v; v.u = ((unsigned int)h) << 16;
    return v.f;
}
__device__ __forceinline__ void gload_lds16(const void* g, void* l) {
    __builtin_amdgcn_global_load_lds((const __attribute__((address_space(1))) void*)g,
                                     (__attribute__((address_space(3))) void*)l, 16, 0, 0);
}

// ---------------- weight prep: transposed bf16 weights ----------------
// wc1[n*512+k] : k<256 -> W1[k][n], else W3[k-256][n]
// wc2[n*512+k] : k<256 -> W2[k][n], else W3[k-256][n]
// nnt[n*256+k] = nnW[k][n]
// aWt[n*96+k]  : k<92 -> aW[k][n], k==92 -> ab[n], else 0
__global__ __launch_bounds__(256) void prep_weights(const float* __restrict__ mlpW,
                                                    const float* __restrict__ nnW,
                                                    const float* __restrict__ aW,
                                                    const float* __restrict__ ab,
                                                    unsigned short* __restrict__ wc1,
                                                    unsigned short* __restrict__ wc2,
                                                    unsigned short* __restrict__ nnt,
                                                    unsigned short* __restrict__ aWt) {
    int idx = blockIdx.x * 256 + threadIdx.x;
    if (idx < 256 * 512) {
        int n = idx >> 9, k = idx & 511;
        float v1 = (k < 256) ? mlpW[k * DD + n] : mlpW[(k + 256) * DD + n];
        wc1[idx] = f2bf(v1);
        wc2[idx] = f2bf(mlpW[(k + 256) * DD + n]);
    }
    if (idx < 256 * 256) {
        int n = idx >> 8, k = idx & 255;
        nnt[idx] = f2bf(nnW[k * DD + n]);
    }
    if (idx < 256 * 96) {
        int n = idx / 96, k = idx - n * 96;
        float v = (k < 92) ? aW[k * DD + n] : (k == 92 ? ab[n] : 0.0f);
        aWt[idx] = f2bf(v);
    }
}

// ---------------- u/v chains + BN fold ----------------
__global__ __launch_bounds__(256) void prep_uv(const float* __restrict__ eW, const float* __restrict__ eb,
                                               const float* __restrict__ mlpW, const float* __restrict__ mlpb,
                                               const float* __restrict__ nnb,
                                               const float* __restrict__ bn_g, const float* __restrict__ bn_b,
                                               const float* __restrict__ bn_m, const float* __restrict__ bn_v,
                                               float* __restrict__ u_all, float* __restrict__ v_all,
                                               float* __restrict__ scale, float* __restrict__ shift) {
    __shared__ float uc[DD], vc[DD];
    int d = threadIdx.x;
    uc[d] = eW[d];
    vc[d] = eb[d];
    float sc = bn_g[d] * rsqrtf(bn_v[d] + 1e-5f);
    scale[d] = sc;
    shift[d] = (nnb[d] - bn_m[d]) * sc + bn_b[d];
    __syncthreads();
    const float* W3 = mlpW + 2 * DD * DD;
    for (int it = 0; it < 4; ++it) {
        float su = 0.f, sv = 0.f;
        for (int k = 0; k < DD; ++k) {
            float w = W3[k * DD + d];
            su += uc[k] * w;
            sv += vc[k] * w;
        }
        sv += mlpb[d];
        u_all[it * DD + d] = su;
        v_all[it * DD + d] = sv;
        __syncthreads();
        uc[d] = su; vc[d] = sv;
        __syncthreads();
    }
}

// ---------------- nf -> bf16 padded [MPAD][96] with bias column ----------------
__global__ __launch_bounds__(256) void nfb_prep(const float* __restrict__ nf, unsigned short* __restrict__ nfb) {
    int idx = blockIdx.x * 256 + threadIdx.x;
    if (idx >= MPAD * 96) return;
    int r = idx / 96, c = idx - r * 96;
    float v;
    if (r < NNODE && c < 92) v = nf[(size_t)r * 92 + c];
    else v = (c == 92) ? 1.0f : 0.0f;
    nfb[idx] = f2bf(v);
}

// ---------------- xinit GEMM: x[M][256] = nfb[M][96] @ aWt^T, single-stage ----------------
__global__ __launch_bounds__(512) void xinit_gemm(const unsigned short* __restrict__ nfb,
                                                  const unsigned short* __restrict__ aWt,
                                                  unsigned short* __restrict__ x) {
    __shared__ unsigned short As[128][96];
    __shared__ unsigned short Bs[256][96];
    const int tid = threadIdx.x;
    const int lane = tid & 63, wid = tid >> 6;
    const int wr = wid >> 2, wc = wid & 3;
    const int m0 = blockIdx.x * 128;
    const int lr = lane & 15, lq = lane >> 4;

    for (int i = tid; i < 128 * 12; i += 512) {
        int row = i / 12, ch = (i - row * 12) * 8;
        gload_lds16(nfb + (size_t)(m0 + row) * 96 + ch, &As[row][ch]);
    }
    for (int i = tid; i < 256 * 12; i += 512) {
        int row = i / 12, ch = (i - row * 12) * 8;
        gload_lds16(aWt + (size_t)row * 96 + ch, &Bs[row][ch]);
    }
    __syncthreads();

    f32x4 acc[4][4];
    #pragma unroll
    for (int m = 0; m < 4; ++m)
        #pragma unroll
        for (int n = 0; n < 4; ++n) { f32x4 z = {0.f,0.f,0.f,0.f}; acc[m][n] = z; }

    #pragma unroll
    for (int h = 0; h < 3; ++h) {
        bf16x8 af[4], bf[4];
        #pragma unroll
        for (int m = 0; m < 4; ++m)
            af[m] = *reinterpret_cast<const bf16x8*>(&As[wr * 64 + m * 16 + lr][h * 32 + lq * 8]);
        #pragma unroll
        for (int n = 0; n < 4; ++n)
            bf[n] = *reinterpret_cast<const bf16x8*>(&Bs[wc * 64 + n * 16 + lr][h * 32 + lq * 8]);
        #pragma unroll
        for (int m = 0; m < 4; ++m)
            #pragma unroll
            for (int n = 0; n < 4; ++n)
                acc[m][n] = __builtin_amdgcn_mfma_f32_16x16x32_bf16(af[m], bf[n], acc[m][n], 0, 0, 0);
    }

    #pragma unroll
    for (int m = 0; m < 4; ++m) {
        const int rb = m0 + wr * 64 + m * 16 + lq * 4;
        #pragma unroll
        for (int n = 0; n < 4; ++n) {
            const int c = wc * 64 + n * 16 + lr;
            #pragma unroll
            for (int j = 0; j < 4; ++j)
                x[(size_t)(rb + j) * DD + c] = f2bf(acc[m][n][j]);
        }
    }
}

// ---------------- CSR build ----------------
__global__ __launch_bounds__(256) void hist_kernel(const int* __restrict__ ei, int* __restrict__ counts) {
    int e = blockIdx.x * 256 + threadIdx.x;
    if (e < NEDGE) atomicAdd(&counts[ei[NEDGE + e]], 1);
}

__global__ __launch_bounds__(256) void scan1(const int* __restrict__ counts, int* __restrict__ blockSums) {
    int t = threadIdx.x;
    int base = blockIdx.x * 1024 + t * 4;
    int s = 0;
    #pragma unroll
    for (int i = 0; i < 4; ++i) { int idx = base + i; if (idx < NNODE) s += counts[idx]; }
    __shared__ int red[256];
    red[t] = s; __syncthreads();
    for (int d = 128; d; d >>= 1) { if (t < d) red[t] += red[t + d]; __syncthreads(); }
    if (t == 0) blockSums[blockIdx.x] = red[0];
}

__global__ __launch_bounds__(64) void scan2(int* __restrict__ blockSums) {
    int t = threadIdx.x;
    int v = (t < NCHUNK) ? blockSums[t] : 0;
    int orig = v;
    #pragma unroll
    for (int d = 1; d < 64; d <<= 1) {
        int o = __shfl_up(v, d);
        if (t >= d) v += o;
    }
    if (t < NCHUNK) blockSums[t] = v - orig;   // exclusive
}

__global__ __launch_bounds__(256) void scan3(const int* __restrict__ counts, const int* __restrict__ blockSums,
                                             int* __restrict__ offsets, int* __restrict__ cursor) {
    int t = threadIdx.x;
    int base = blockIdx.x * 1024 + t * 4;
    int c[4]; int s = 0;
    #pragma unroll
    for (int i = 0; i < 4; ++i) { int idx = base + i; c[i] = (idx < NNODE) ? counts[idx] : 0; s += c[i]; }
    __shared__ int lds[256];
    lds[t] = s; __syncthreads();
    for (int d = 1; d < 256; d <<= 1) {
        int v = (t >= d) ? lds[t - d] : 0;
        __syncthreads();
        lds[t] += v;
        __syncthreads();
    }
    int off = blockSums[blockIdx.x] + lds[t] - s;
    #pragma unroll
    for (int i = 0; i < 4; ++i) {
        int idx = base + i;
        if (idx < NNODE) { offsets[idx] = off; cursor[idx] = off; off += c[i]; }
    }
}

__global__ __launch_bounds__(256) void scatter_kernel(const int* __restrict__ ei, const float* __restrict__ aw,
                                                      int* __restrict__ cursor,
                                                      int* __restrict__ srow, float* __restrict__ sw) {
    int e = blockIdx.x * 256 + threadIdx.x;
    if (e < NEDGE) {
        int c = ei[NEDGE + e];
        int pos = atomicAdd(&cursor[c], 1);
        srow[pos] = ei[e];
        sw[pos] = aw[e];
    }
}

// ---------------- fused P/Q GEMM ----------------
// accP = [x | Pin] @ wc1^T ; accQ = [x | Qin] @ wc2^T  (K = 256 or 512)
// x-phase K-chunks share one A-tile for both outputs.
__global__ __launch_bounds__(512) void gemm_pq(const unsigned short* __restrict__ X,
                                               const unsigned short* __restrict__ Pin,
                                               const unsigned short* __restrict__ Qin,
                                               const unsigned short* __restrict__ B1,
                                               const unsigned short* __restrict__ B2,
                                               unsigned short* __restrict__ Pout,
                                               unsigned short* __restrict__ Qout,
                                               int haspq) {
    __shared__ unsigned short As[2][128][64];
    __shared__ unsigned short Bs[2][256][64];
    const int tid = threadIdx.x;
    const int lane = tid & 63, wid = tid >> 6;
    const int wr = wid >> 2, wc = wid & 3;
    const int m0 = blockIdx.x * 128;
    const int lr = lane & 15, lq = lane >> 4;
    const int srow = tid >> 3;        // 0..63
    const int scol = (tid & 7) * 8;   // element col

    f32x4 accP[4][4], accQ[4][4];
    #pragma unroll
    for (int m = 0; m < 4; ++m)
        #pragma unroll
        for (int n = 0; n < 4; ++n) {
            f32x4 z = {0.f,0.f,0.f,0.f};
            accP[m][n] = z; accQ[m][n] = z;
        }

    const int nk = haspq ? 8 : 4;
    for (int kt = 0; kt < nk; ++kt) {
        const int k0 = kt << 6;
        const bool xph = (kt < 4);
        if (xph) {
            #pragma unroll
            for (int p = 0; p < 2; ++p) {
                int row = p * 64 + srow;
                gload_lds16(X + (size_t)(m0 + row) * DD + k0 + scol, &As[0][row][scol]);
            }
        } else {
            #pragma unroll
            for (int p = 0; p < 2; ++p) {
                int row = p * 64 + srow;
                gload_lds16(Pin + (size_t)(m0 + row) * DD + (k0 - 256) + scol, &As[0][row][scol]);
                gload_lds16(Qin + (size_t)(m0 + row) * DD + (k0 - 256) + scol, &As[1][row][scol]);
            }
        }
        #pragma unroll
        for (int p = 0; p < 4; ++p) {
            int row = p * 64 + srow;
            gload_lds16(B1 + (size_t)row * 512 + k0 + scol, &Bs[0][row][scol]);
            gload_lds16(B2 + (size_t)row * 512 + k0 + scol, &Bs[1][row][scol]);
        }
        __syncthreads();
        if (xph) {
            #pragma unroll
            for (int h = 0; h < 2; ++h) {
                bf16x8 af[4], bP[4], bQ[4];
                #pragma unroll
                for (int m = 0; m < 4; ++m)
                    af[m] = *reinterpret_cast<const bf16x8*>(&As[0][wr * 64 + m * 16 + lr][h * 32 + lq * 8]);
                #pragma unroll
                for (int n = 0; n < 4; ++n) {
                    bP[n] = *reinterpret_cast<const bf16x8*>(&Bs[0][wc * 64 + n * 16 + lr][h * 32 + lq * 8]);
                    bQ[n] = *reinterpret_cast<const bf16x8*>(&Bs[1][wc * 64 + n * 16 + lr][h * 32 + lq * 8]);
                }
                #pragma unroll
                for (int m = 0; m < 4; ++m)
                    #pragma unroll
                    for (int n = 0; n < 4; ++n) {
                        accP[m][n] = __builtin_amdgcn_mfma_f32_16x16x32_bf16(af[m], bP[n], accP[m][n], 0, 0, 0);
                        accQ[m][n] = __builtin_amdgcn_mfma_f32_16x16x32_bf16(af[m], bQ[n], accQ[m][n], 0, 0, 0);
                    }
            }
        } else {
            #pragma unroll
            for (int h = 0; h < 2; ++h) {
                bf16x8 aP[4], aQ[4], bP[4], bQ[4];
                #pragma unroll
                for (int m = 0; m < 4; ++m) {
                    aP[m] = *reinterpret_cast<const bf16x8*>(&As[0][wr * 64 + m * 16 + lr][h * 32 + lq * 8]);
                    aQ[m] = *reinterpret_cast<const bf16x8*>(&As[1][wr * 64 + m * 16 + lr][h * 32 + lq * 8]);
                }
                #pragma unroll
                for (int n = 0; n < 4; ++n) {
                    bP[n] = *reinterpret_cast<const bf16x8*>(&Bs[0][wc * 64 + n * 16 + lr][h * 32 + lq * 8]);
                    bQ[n] = *reinterpret_cast<const bf16x8*>(&Bs[1][wc * 64 + n * 16 + lr][h * 32 + lq * 8]);
                }
                #pragma unroll
                for (int m = 0; m < 4; ++m)
                    #pragma unroll
                    for (int n = 0; n < 4; ++n) {
                        accP[m][n] = __builtin_amdgcn_mfma_f32_16x16x32_bf16(aP[m], bP[n], accP[m][n], 0, 0, 0);
                        accQ[m][n] = __builtin_amdgcn_mfma_f32_16x16x32_bf16(aQ[m], bQ[n], accQ[m][n], 0, 0, 0);
                    }
            }
        }
        __syncthreads();
    }

    #pragma unroll
    for (int m = 0; m < 4; ++m) {
        const int rb = m0 + wr * 64 + m * 16 + lq * 4;
        #pragma unroll
        for (int n = 0; n < 4; ++n) {
            const int c = wc * 64 + n * 16 + lr;
            #pragma unroll
            for (int j = 0; j < 4; ++j) {
                const size_t idx = (size_t)(rb + j) * DD + c;
                Pout[idx] = f2bf(accP[m][n][j]);
                Qout[idx] = f2bf(accQ[m][n][j]);
            }
        }
    }
}

// ---------------- layer-out GEMM: x = relu((aggB @ nnt^T) * scale + shift) ----------------
__global__ __launch_bounds__(512) void gemm_bn(const unsigned short* __restrict__ A,
                                               const unsigned short* __restrict__ Bt,
                                               unsigned short* __restrict__ Cout,
                                               const float* __restrict__ scale,
                                               const float* __restrict__ shift) {
    __shared__ unsigned short As[128][64];
    __shared__ unsigned short Bs[256][64];
    const int tid = threadIdx.x;
    const int lane = tid & 63, wid = tid >> 6;
    const int wr = wid >> 2, wc = wid & 3;
    const int m0 = blockIdx.x * 128;
    const int lr = lane & 15, lq = lane >> 4;
    const int srow = tid >> 3;
    const int scol = (tid & 7) * 8;

    f32x4 acc[4][4];
    #pragma unroll
    for (int m = 0; m < 4; ++m)
        #pragma unroll
        for (int n = 0; n < 4; ++n) { f32x4 z = {0.f,0.f,0.f,0.f}; acc[m][n] = z; }

    for (int kt = 0; kt < 4; ++kt) {
        const int k0 = kt << 6;
        #pragma unroll
        for (int p = 0; p < 2; ++p) {
            int row = p * 64 + srow;
            gload_lds16(A + (size_t)(m0 + row) * DD + k0 + scol, &As[row][scol]);
        }
        #pragma unroll
        for (int p = 0; p < 4; ++p) {
            int row = p * 64 + srow;
            gload_lds16(Bt + (size_t)row * DD + k0 + scol, &Bs[row][scol]);
        }
        __syncthreads();
        #pragma unroll
        for (int h = 0; h < 2; ++h) {
            bf16x8 af[4], bfr[4];
            #pragma unroll
            for (int m = 0; m < 4; ++m)
                af[m] = *reinterpret_cast<const bf16x8*>(&As[wr * 64 + m * 16 + lr][h * 32 + lq * 8]);
            #pragma unroll
            for (int n = 0; n < 4; ++n)
                bfr[n] = *reinterpret_cast<const bf16x8*>(&Bs[wc * 64 + n * 16 + lr][h * 32 + lq * 8]);
            #pragma unroll
            for (int m = 0; m < 4; ++m)
                #pragma unroll
                for (int n = 0; n < 4; ++n)
                    acc[m][n] = __builtin_amdgcn_mfma_f32_16x16x32_bf16(af[m], bfr[n], acc[m][n], 0, 0, 0);
        }
        __syncthreads();
    }

    #pragma unroll
    for (int m = 0; m < 4; ++m) {
        const int rb = m0 + wr * 64 + m * 16 + lq * 4;
        #pragma unroll
        for (int n = 0; n < 4; ++n) {
            const int c = wc * 64 + n * 16 + lr;
            #pragma unroll
            for (int j = 0; j < 4; ++j) {
                const size_t idx = (size_t)(rb + j) * DD + c;
                float y = fmaxf(acc[m][n][j] * scale[c] + shift[c], 0.f);
                Cout[idx] = f2bf(y);
            }
        }
    }
}

// ---------------- edge pass (CSR gather): one wave per node, 2 edges/iter ----------------
// aggB[n] = x[n] + sum_{e: col(e)=n} relu( x[r]+P[r] + Q[n] + w*u + v )
__global__ __launch_bounds__(256) void edge_csr(const int* __restrict__ offsets, const int* __restrict__ counts,
                                                const int* __restrict__ srow, const float* __restrict__ sw,
                                                const unsigned short* __restrict__ X,
                                                const unsigned short* __restrict__ P,
                                                const unsigned short* __restrict__ Q,
                                                const float* __restrict__ u, const float* __restrict__ v,
                                                unsigned short* __restrict__ aggB) {
    const int lane = threadIdx.x & 63, wid = threadIdx.x >> 6;
    const int n = blockIdx.x * 4 + wid;
    if (n >= NNODE) return;
    const int start = offsets[n];
    const int deg = counts[n];
    const int sub = lane & 31, h = lane >> 5;

    const us8* X8 = (const us8*)X;
    const us8* P8 = (const us8*)P;

    float4 u0 = ((const float4*)u)[sub * 2], u1 = ((const float4*)u)[sub * 2 + 1];
    float4 v0 = ((const float4*)v)[sub * 2], v1 = ((const float4*)v)[sub * 2 + 1];
    float uu[8] = {u0.x, u0.y, u0.z, u0.w, u1.x, u1.y, u1.z, u1.w};
    float vv[8] = {v0.x, v0.y, v0.z, v0.w, v1.x, v1.y, v1.z, v1.w};

    us8 qv = ((const us8*)Q)[(size_t)n * 32 + sub];
    float base[8];
    #pragma unroll
    for (int c = 0; c < 8; ++c) base[c] = bf2f(qv[c]) + vv[c];

    float a[8];
    us8 xv = X8[(size_t)n * 32 + sub];
    #pragma unroll
    for (int c = 0; c < 8; ++c) a[c] = (h == 0) ? bf2f(xv[c]) : 0.f;

    for (int b0 = 0; b0 < deg; b0 += 64) {
        int m = deg - b0; if (m > 64) m = 64;
        int myr = 0; float myw = 0.f;
        if (lane < m) { myr = srow[start + b0 + lane]; myw = sw[start + b0 + lane]; }
        int iters = (m + 1) >> 1;
        for (int j = 0; j < iters; ++j) {
            int el = 2 * j + h;
            int r = __shfl(myr, el);
            float w = __shfl(myw, el);
            if (el < m) {
                us8 x2 = X8[(size_t)r * 32 + sub];
                us8 p2 = P8[(size_t)r * 32 + sub];
                #pragma unroll
                for (int c = 0; c < 8; ++c)
                    a[c] += fmaxf(bf2f(x2[c]) + bf2f(p2[c]) + base[c] + w * uu[c], 0.f);
            }
        }
    }
    #pragma unroll
    for (int c = 0; c < 8; ++c) a[c] += __shfl_xor(a[c], 32);
    if (h == 0) {
        us8 o;
        #pragma unroll
        for (int c = 0; c < 8; ++c) o[c] = f2bf(a[c]);
        ((us8*)aggB)[(size_t)n * 32 + sub] = o;
    }
}

// ---------------- pooling: pooled[batch[n]] += x[n], batch sorted ----------------
__global__ __launch_bounds__(256) void pool_kernel(const unsigned short* __restrict__ x,
                                                   const int* __restrict__ batch,
                                                   float* __restrict__ pooled) {
    const int lane = threadIdx.x & 63, wid = threadIdx.x >> 6;
    const int base = (blockIdx.x * 4 + wid) * 8;
    float4 acc = make_float4(0.f, 0.f, 0.f, 0.f);
    int gcur = -1;
    for (int i = 0; i < 8; ++i) {
        int n = base + i;
        if (n >= NNODE) break;
        int g = batch[n];
        if (g != gcur) {
            if (gcur >= 0) {
                float* pp = pooled + (size_t)gcur * DD + lane * 4;
                unsafeAtomicAdd(pp + 0, acc.x);
                unsafeAtomicAdd(pp + 1, acc.y);
                unsafeAtomicAdd(pp + 2, acc.z);
                unsafeAtomicAdd(pp + 3, acc.w);
            }
            gcur = g;
            acc = make_float4(0.f, 0.f, 0.f, 0.f);
        }
        ushort4 xv = ((const ushort4*)x)[(size_t)n * 64 + lane];
        acc.x += bf2f(xv.x); acc.y += bf2f(xv.y);
        acc.z += bf2f(xv.z); acc.w += bf2f(xv.w);
    }
    if (gcur >= 0) {
        float* pp = pooled + (size_t)gcur * DD + lane * 4;
        unsafeAtomicAdd(pp + 0, acc.x);
        unsafeAtomicAdd(pp + 1, acc.y);
        unsafeAtomicAdd(pp + 2, acc.z);
        unsafeAtomicAdd(pp + 3, acc.w);
    }
}

// ---------------- out: d_out = pooled @ outW + outb ----------------
__global__ __launch_bounds__(64) void out_kernel(const float* __restrict__ pooled,
                                                 const float* __restrict__ outW,
                                                 const float* __restrict__ outb,
                                                 float* __restrict__ out) {
    const int g = blockIdx.x, lane = threadIdx.x;
    float4 p = ((const float4*)pooled)[g * 64 + lane];
    float s[6];
    #pragma unroll
    for (int j = 0; j < 6; ++j) {
        float a = p.x * outW[(lane * 4 + 0) * 6 + j] + p.y * outW[(lane * 4 + 1) * 6 + j] +
                  p.z * outW[(lane * 4 + 2) * 6 + j] + p.w * outW[(lane * 4 + 3) * 6 + j];
        #pragma unroll
        for (int off = 32; off; off >>= 1) a += __shfl_down(a, off);
        s[j] = a;
    }
    if (lane == 0) {
        #pragma unroll
        for (int j = 0; j < 6; ++j) out[g * 6 + j] = s[j] + outb[j];
    }
}

extern "C" void kernel_launch(void* const* d_in, const int* in_sizes, int n_in,
                              void* d_out, int out_size, void* d_ws, size_t ws_size,
                              hipStream_t stream) {
    const float* nf    = (const float*)d_in[0];
    const int*   ei    = (const int*)d_in[1];
    const float* aw    = (const float*)d_in[2];
    const int*   batch = (const int*)d_in[3];
    const float* aW    = (const float*)d_in[4];
    const float* ab    = (const float*)d_in[5];
    const float* eW    = (const float*)d_in[6];
    const float* eb    = (const float*)d_in[7];
    const float* mlpW  = (const float*)d_in[8];
    const float* mlpb  = (const float*)d_in[9];
    const float* nnW   = (const float*)d_in[10];
    const float* nnb   = (const float*)d_in[11];
    const float* bn_g  = (const float*)d_in[12];
    const float* bn_b  = (const float*)d_in[13];
    const float* bn_m  = (const float*)d_in[14];
    const float* bn_v  = (const float*)d_in[15];
    const float* outW  = (const float*)d_in[16];
    const float* outb  = (const float*)d_in[17];
    float* out = (float*)d_out;

    char* ws = (char*)d_ws;
    size_t off = 0;
    auto alloc = [&](size_t bytes) -> void* {
        void* p = ws + off;
        off += (bytes + 255) & ~(size_t)255;
        return p;
    };
    unsigned short* x    = (unsigned short*)alloc((size_t)MPAD * DD * 2);
    unsigned short* P    = (unsigned short*)alloc((size_t)MPAD * DD * 2);
    unsigned short* Q    = (unsigned short*)alloc((size_t)MPAD * DD * 2);
    unsigned short* aggB = (unsigned short*)alloc((size_t)MPAD * DD * 2);
    unsigned short* nfb  = (unsigned short*)alloc((size_t)MPAD * 96 * 2);
    unsigned short* wc1  = (unsigned short*)alloc(256 * 512 * 2);
    unsigned short* wc2  = (unsigned short*)alloc(256 * 512 * 2);
    unsigned short* nnt  = (unsigned short*)alloc(256 * 256 * 2);
    unsigned short* aWt  = (unsigned short*)alloc(256 * 96 * 2);
    float* u_all = (float*)alloc(4 * DD * 4);
    float* v_all = (float*)alloc(4 * DD * 4);
    float* scale = (float*)alloc(DD * 4);
    float* shift = (float*)alloc(DD * 4);
    float* pooled = (float*)alloc((size_t)NGRAPH * DD * 4);
    int* counts  = (int*)alloc((size_t)NNODE * 4);
    int* offsets = (int*)alloc((size_t)NNODE * 4);
    int* cursor  = (int*)alloc((size_t)NNODE * 4);
    int* blockSums = (int*)alloc(NCHUNK * 4);
    int* srowB   = (int*)alloc((size_t)NEDGE * 4);
    float* swB   = (float*)alloc((size_t)NEDGE * 4);
    (void)ws_size; (void)in_sizes; (void)n_in; (void)out_size;

    // one-time prep
    prep_weights<<<512, 256, 0, stream>>>(mlpW, nnW, aW, ab, wc1, wc2, nnt, aWt);
    prep_uv<<<1, 256, 0, stream>>>(eW, eb, mlpW, mlpb, nnb, bn_g, bn_b, bn_m, bn_v,
                                   u_all, v_all, scale, shift);
    nfb_prep<<<(MPAD * 96 + 255) / 256, 256, 0, stream>>>(nf, nfb);
    xinit_gemm<<<MPAD / 128, 512, 0, stream>>>(nfb, aWt, x);

    // CSR build (once; shared by all 4 layers)
    hipMemsetAsync(counts, 0, (size_t)NNODE * 4, stream);
    hist_kernel<<<(NEDGE + 255) / 256, 256, 0, stream>>>(ei, counts);
    scan1<<<NCHUNK, 256, 0, stream>>>(counts, blockSums);
    scan2<<<1, 64, 0, stream>>>(blockSums);
    scan3<<<NCHUNK, 256, 0, stream>>>(counts, blockSums, offsets, cursor);
    scatter_kernel<<<(NEDGE + 255) / 256, 256, 0, stream>>>(ei, aw, cursor, srowB, swB);

    for (int k = 0; k < 4; ++k) {
        gemm_pq<<<MPAD / 128, 512, 0, stream>>>(x, P, Q, wc1, wc2, P, Q, k ? 1 : 0);
        edge_csr<<<(NNODE + 3) / 4, 256, 0, stream>>>(offsets, counts, srowB, swB, x, P, Q,
                                                      u_all + k * DD, v_all + k * DD, aggB);
        gemm_bn<<<MPAD / 128, 512, 0, stream>>>(aggB, nnt, x, scale, shift);
    }

    hipMemsetAsync(pooled, 0, (size_t)NGRAPH * DD * 4, stream);
    pool_kernel<<<(NNODE + 31) / 32, 256, 0, stream>>>(x, batch, pooled);
    out_kernel<<<NGRAPH, 64, 0, stream>>>(pooled, outW, outb, out);
}

// Round 4
// 519.594 us; speedup vs baseline: 6.1158x; 1.1939x over previous
//
#include <hip/hip_runtime.h>
#include <stdint.h>

#define DD 256
#define NNODE 60000
#define MPAD 60032            // 469 * 128
#define NEDGE 200000
#define NGRAPH 1500
#define NCHUNK 59             // ceil(60000/1024)

typedef __bf16 bf16x8 __attribute__((ext_vector_type(8)));
typedef float f32x4 __attribute__((ext_vector_type(4)));
typedef unsigned short us8 __attribute__((ext_vector_type(8)));

__device__ __forceinline__ unsigned short f2bf(float f) {
    union { float f; unsigned int u; } v; v.f = f;
    unsigned int r = v.u + 0x7FFFu + ((v.u >> 16) & 1u);
    return (unsigned short)(r >> 16);
}
__device__ __forceinline__ float bf2f(unsigned short h) {
    union { unsigned int u; float f; } v; v.u = ((unsigned int)h) << 16;
    return v.f;
}
__device__ __forceinline__ void gload_lds16(const void* g, void* l) {
    __builtin_amdgcn_global_load_lds((const __attribute__((address_space(1))) void*)g,
                                     (__attribute__((address_space(3))) void*)l, 16, 0, 0);
}

// ---------------- weight prep: transposed bf16 weights ----------------
__global__ __launch_bounds__(256) void prep_weights(const float* __restrict__ mlpW,
                                                    const float* __restrict__ nnW,
                                                    const float* __restrict__ aW,
                                                    const float* __restrict__ ab,
                                                    unsigned short* __restrict__ wc1,
                                                    unsigned short* __restrict__ wc2,
                                                    unsigned short* __restrict__ nnt,
                                                    unsigned short* __restrict__ aWt) {
    int idx = blockIdx.x * 256 + threadIdx.x;
    if (idx < 256 * 512) {
        int n = idx >> 9, k = idx & 511;
        float v1 = (k < 256) ? mlpW[k * DD + n] : mlpW[(k + 256) * DD + n];
        wc1[idx] = f2bf(v1);
        wc2[idx] = f2bf(mlpW[(k + 256) * DD + n]);
    }
    if (idx < 256 * 256) {
        int n = idx >> 8, k = idx & 255;
        nnt[idx] = f2bf(nnW[k * DD + n]);
    }
    if (idx < 256 * 96) {
        int n = idx / 96, k = idx - n * 96;
        float v = (k < 92) ? aW[k * DD + n] : (k == 92 ? ab[n] : 0.0f);
        aWt[idx] = f2bf(v);
    }
}

// ---------------- u/v chains + BN fold ----------------
__global__ __launch_bounds__(256) void prep_uv(const float* __restrict__ eW, const float* __restrict__ eb,
                                               const float* __restrict__ mlpW, const float* __restrict__ mlpb,
                                               const float* __restrict__ nnb,
                                               const float* __restrict__ bn_g, const float* __restrict__ bn_b,
                                               const float* __restrict__ bn_m, const float* __restrict__ bn_v,
                                               float* __restrict__ u_all, float* __restrict__ v_all,
                                               float* __restrict__ scale, float* __restrict__ shift) {
    __shared__ float uc[DD], vc[DD];
    int d = threadIdx.x;
    uc[d] = eW[d];
    vc[d] = eb[d];
    float sc = bn_g[d] * rsqrtf(bn_v[d] + 1e-5f);
    scale[d] = sc;
    shift[d] = (nnb[d] - bn_m[d]) * sc + bn_b[d];
    __syncthreads();
    const float* W3 = mlpW + 2 * DD * DD;
    for (int it = 0; it < 4; ++it) {
        float su = 0.f, sv = 0.f;
        for (int k = 0; k < DD; ++k) {
            float w = W3[k * DD + d];
            su += uc[k] * w;
            sv += vc[k] * w;
        }
        sv += mlpb[d];
        u_all[it * DD + d] = su;
        v_all[it * DD + d] = sv;
        __syncthreads();
        uc[d] = su; vc[d] = sv;
        __syncthreads();
    }
}

// ---------------- nf -> bf16 padded [MPAD][96] with bias column ----------------
__global__ __launch_bounds__(256) void nfb_prep(const float* __restrict__ nf, unsigned short* __restrict__ nfb) {
    int idx = blockIdx.x * 256 + threadIdx.x;
    if (idx >= MPAD * 96) return;
    int r = idx / 96, c = idx - r * 96;
    float v;
    if (r < NNODE && c < 92) v = nf[(size_t)r * 92 + c];
    else v = (c == 92) ? 1.0f : 0.0f;
    nfb[idx] = f2bf(v);
}

// ---------------- xinit GEMM: x[M][256] = nfb[M][96] @ aWt^T, single-stage ----------------
__global__ __launch_bounds__(512) void xinit_gemm(const unsigned short* __restrict__ nfb,
                                                  const unsigned short* __restrict__ aWt,
                                                  unsigned short* __restrict__ x) {
    __shared__ unsigned short As[128][96];
    __shared__ unsigned short Bs[256][96];
    const int tid = threadIdx.x;
    const int lane = tid & 63, wid = tid >> 6;
    const int wr = wid >> 2, wc = wid & 3;
    const int m0 = blockIdx.x * 128;
    const int lr = lane & 15, lq = lane >> 4;

    for (int i = tid; i < 128 * 12; i += 512) {
        int row = i / 12, ch = (i - row * 12) * 8;
        gload_lds16(nfb + (size_t)(m0 + row) * 96 + ch, &As[row][ch]);
    }
    for (int i = tid; i < 256 * 12; i += 512) {
        int row = i / 12, ch = (i - row * 12) * 8;
        gload_lds16(aWt + (size_t)row * 96 + ch, &Bs[row][ch]);
    }
    __syncthreads();

    f32x4 acc[4][4];
    #pragma unroll
    for (int m = 0; m < 4; ++m)
        #pragma unroll
        for (int n = 0; n < 4; ++n) { f32x4 z = {0.f,0.f,0.f,0.f}; acc[m][n] = z; }

    #pragma unroll
    for (int h = 0; h < 3; ++h) {
        bf16x8 af[4], bf[4];
        #pragma unroll
        for (int m = 0; m < 4; ++m)
            af[m] = *reinterpret_cast<const bf16x8*>(&As[wr * 64 + m * 16 + lr][h * 32 + lq * 8]);
        #pragma unroll
        for (int n = 0; n < 4; ++n)
            bf[n] = *reinterpret_cast<const bf16x8*>(&Bs[wc * 64 + n * 16 + lr][h * 32 + lq * 8]);
        #pragma unroll
        for (int m = 0; m < 4; ++m)
            #pragma unroll
            for (int n = 0; n < 4; ++n)
                acc[m][n] = __builtin_amdgcn_mfma_f32_16x16x32_bf16(af[m], bf[n], acc[m][n], 0, 0, 0);
    }

    #pragma unroll
    for (int m = 0; m < 4; ++m) {
        const int rb = m0 + wr * 64 + m * 16 + lq * 4;
        #pragma unroll
        for (int n = 0; n < 4; ++n) {
            const int c = wc * 64 + n * 16 + lr;
            #pragma unroll
            for (int j = 0; j < 4; ++j)
                x[(size_t)(rb + j) * DD + c] = f2bf(acc[m][n][j]);
        }
    }
}

// ---------------- CSR build ----------------
__global__ __launch_bounds__(256) void hist_kernel(const int* __restrict__ ei, int* __restrict__ counts) {
    int e = blockIdx.x * 256 + threadIdx.x;
    if (e < NEDGE) atomicAdd(&counts[ei[NEDGE + e]], 1);
}

__global__ __launch_bounds__(256) void scan1(const int* __restrict__ counts, int* __restrict__ blockSums) {
    int t = threadIdx.x;
    int base = blockIdx.x * 1024 + t * 4;
    int s = 0;
    #pragma unroll
    for (int i = 0; i < 4; ++i) { int idx = base + i; if (idx < NNODE) s += counts[idx]; }
    __shared__ int red[256];
    red[t] = s; __syncthreads();
    for (int d = 128; d; d >>= 1) { if (t < d) red[t] += red[t + d]; __syncthreads(); }
    if (t == 0) blockSums[blockIdx.x] = red[0];
}

__global__ __launch_bounds__(64) void scan2(int* __restrict__ blockSums) {
    int t = threadIdx.x;
    int v = (t < NCHUNK) ? blockSums[t] : 0;
    int orig = v;
    #pragma unroll
    for (int d = 1; d < 64; d <<= 1) {
        int o = __shfl_up(v, d);
        if (t >= d) v += o;
    }
    if (t < NCHUNK) blockSums[t] = v - orig;   // exclusive
}

__global__ __launch_bounds__(256) void scan3(const int* __restrict__ counts, const int* __restrict__ blockSums,
                                             int* __restrict__ offsets, int* __restrict__ cursor) {
    int t = threadIdx.x;
    int base = blockIdx.x * 1024 + t * 4;
    int c[4]; int s = 0;
    #pragma unroll
    for (int i = 0; i < 4; ++i) { int idx = base + i; c[i] = (idx < NNODE) ? counts[idx] : 0; s += c[i]; }
    __shared__ int lds[256];
    lds[t] = s; __syncthreads();
    for (int d = 1; d < 256; d <<= 1) {
        int v = (t >= d) ? lds[t - d] : 0;
        __syncthreads();
        lds[t] += v;
        __syncthreads();
    }
    int off = blockSums[blockIdx.x] + lds[t] - s;
    #pragma unroll
    for (int i = 0; i < 4; ++i) {
        int idx = base + i;
        if (idx < NNODE) { offsets[idx] = off; cursor[idx] = off; off += c[i]; }
    }
}

__global__ __launch_bounds__(256) void scatter_kernel(const int* __restrict__ ei, const float* __restrict__ aw,
                                                      int* __restrict__ cursor,
                                                      int* __restrict__ srow, float* __restrict__ sw) {
    int e = blockIdx.x * 256 + threadIdx.x;
    if (e < NEDGE) {
        int c = ei[NEDGE + e];
        int pos = atomicAdd(&cursor[c], 1);
        srow[pos] = ei[e];
        sw[pos] = aw[e];
    }
}

// ---------------- GEMM: C[M x 256] = A[M x Ktot] * B^T, bf16 MFMA, swizzled LDS ----------------
// 48 KB LDS (As 16K + Bs 32K) -> ~2 blocks/CU. XOR-swizzle: global source column
// chunk pre-swizzled (rule 21: gload_lds dest must stay linear), ds_read applies
// the same XOR -> conflict-free fragment reads.
// EPI 0: Cout = C (P / Q update; in-place over A1 safe: block reads only its own rows)
// EPI 1: Cout = relu(C*scale+shift)  (BN epilogue)
template <int EPI>
__global__ __launch_bounds__(512) void gemm_kernel(
    const unsigned short* __restrict__ A0,
    const unsigned short* __restrict__ A1,
    const unsigned short* __restrict__ Bt, int btStride, int Ktot,
    unsigned short* __restrict__ Cout,
    const float* __restrict__ scale, const float* __restrict__ shift) {
    __shared__ unsigned short As[128][64];
    __shared__ unsigned short Bs[256][64];
    const int tid = threadIdx.x;
    const int lane = tid & 63, wid = tid >> 6;
    const int wr = wid >> 2, wc = wid & 3;
    const int m0 = blockIdx.x * 128;
    const int lr = lane & 15, lq = lane >> 4;
    const int srow = tid >> 3;                    // 0..63
    const int jphys = tid & 7;                    // 16B chunk within row (LDS, linear)
    const int jlog = jphys ^ (srow & 7);          // pre-swizzled global source chunk
    const int scol_g = jlog * 8;                  // global element col
    const int scol_l = jphys * 8;                 // LDS element col
    const int xorj = (lr & 7);                    // read-side XOR (row&7 == lr&7 here)

    f32x4 acc[4][4];
    #pragma unroll
    for (int m = 0; m < 4; ++m)
        #pragma unroll
        for (int n = 0; n < 4; ++n) { f32x4 z = {0.f,0.f,0.f,0.f}; acc[m][n] = z; }

    const int nk = Ktot >> 6;
    for (int kt = 0; kt < nk; ++kt) {
        const int k0 = kt << 6;
        const unsigned short* Ap; int ka;
        if (k0 < 256) { Ap = A0; ka = k0; } else { Ap = A1; ka = k0 - 256; }
        #pragma unroll
        for (int p = 0; p < 2; ++p) {
            int row = p * 64 + srow;
            gload_lds16(Ap + (size_t)(m0 + row) * DD + ka + scol_g, &As[row][scol_l]);
        }
        #pragma unroll
        for (int p = 0; p < 4; ++p) {
            int row = p * 64 + srow;
            gload_lds16(Bt + (size_t)row * btStride + k0 + scol_g, &Bs[row][scol_l]);
        }
        __syncthreads();
        #pragma unroll
        for (int h = 0; h < 2; ++h) {
            const int jp = ((h * 4 + lq) ^ xorj) * 8;   // swizzled read column
            bf16x8 af[4], bfr[4];
            #pragma unroll
            for (int m = 0; m < 4; ++m)
                af[m] = *reinterpret_cast<const bf16x8*>(&As[wr * 64 + m * 16 + lr][jp]);
            #pragma unroll
            for (int n = 0; n < 4; ++n)
                bfr[n] = *reinterpret_cast<const bf16x8*>(&Bs[wc * 64 + n * 16 + lr][jp]);
            #pragma unroll
            for (int m = 0; m < 4; ++m)
                #pragma unroll
                for (int n = 0; n < 4; ++n)
                    acc[m][n] = __builtin_amdgcn_mfma_f32_16x16x32_bf16(af[m], bfr[n], acc[m][n], 0, 0, 0);
        }
        __syncthreads();
    }

    #pragma unroll
    for (int m = 0; m < 4; ++m) {
        const int rb = m0 + wr * 64 + m * 16 + lq * 4;
        #pragma unroll
        for (int n = 0; n < 4; ++n) {
            const int c = wc * 64 + n * 16 + lr;
            #pragma unroll
            for (int j = 0; j < 4; ++j) {
                const size_t idx = (size_t)(rb + j) * DD + c;
                if (EPI == 0) {
                    Cout[idx] = f2bf(acc[m][n][j]);
                } else {
                    float y = fmaxf(acc[m][n][j] * scale[c] + shift[c], 0.f);
                    Cout[idx] = f2bf(y);
                }
            }
        }
    }
}

// ---------------- edge pass (CSR gather): one wave per node, 2 edges/iter ----------------
// aggB[n] = x[n] + sum_{e: col(e)=n} relu( x[r]+P[r] + Q[n] + w*u + v )
__global__ __launch_bounds__(256) void edge_csr(const int* __restrict__ offsets, const int* __restrict__ counts,
                                                const int* __restrict__ srow, const float* __restrict__ sw,
                                                const unsigned short* __restrict__ X,
                                                const unsigned short* __restrict__ P,
                                                const unsigned short* __restrict__ Q,
                                                const float* __restrict__ u, const float* __restrict__ v,
                                                unsigned short* __restrict__ aggB) {
    const int lane = threadIdx.x & 63, wid = threadIdx.x >> 6;
    const int n = blockIdx.x * 4 + wid;
    if (n >= NNODE) return;
    const int start = offsets[n];
    const int deg = counts[n];
    const int sub = lane & 31, h = lane >> 5;

    const us8* X8 = (const us8*)X;
    const us8* P8 = (const us8*)P;

    float4 u0 = ((const float4*)u)[sub * 2], u1 = ((const float4*)u)[sub * 2 + 1];
    float4 v0 = ((const float4*)v)[sub * 2], v1 = ((const float4*)v)[sub * 2 + 1];
    float uu[8] = {u0.x, u0.y, u0.z, u0.w, u1.x, u1.y, u1.z, u1.w};
    float vv[8] = {v0.x, v0.y, v0.z, v0.w, v1.x, v1.y, v1.z, v1.w};

    us8 qv = ((const us8*)Q)[(size_t)n * 32 + sub];
    float base[8];
    #pragma unroll
    for (int c = 0; c < 8; ++c) base[c] = bf2f(qv[c]) + vv[c];

    float a[8];
    us8 xv = X8[(size_t)n * 32 + sub];
    #pragma unroll
    for (int c = 0; c < 8; ++c) a[c] = (h == 0) ? bf2f(xv[c]) : 0.f;

    for (int b0 = 0; b0 < deg; b0 += 64) {
        int m = deg - b0; if (m > 64) m = 64;
        int myr = 0; float myw = 0.f;
        if (lane < m) { myr = srow[start + b0 + lane]; myw = sw[start + b0 + lane]; }
        int iters = (m + 1) >> 1;
        for (int j = 0; j < iters; ++j) {
            int el = 2 * j + h;
            int r = __shfl(myr, el);
            float w = __shfl(myw, el);
            if (el < m) {
                us8 x2 = X8[(size_t)r * 32 + sub];
                us8 p2 = P8[(size_t)r * 32 + sub];
                #pragma unroll
                for (int c = 0; c < 8; ++c)
                    a[c] += fmaxf(bf2f(x2[c]) + bf2f(p2[c]) + base[c] + w * uu[c], 0.f);
            }
        }
    }
    #pragma unroll
    for (int c = 0; c < 8; ++c) a[c] += __shfl_xor(a[c], 32);
    if (h == 0) {
        us8 o;
        #pragma unroll
        for (int c = 0; c < 8; ++c) o[c] = f2bf(a[c]);
        ((us8*)aggB)[(size_t)n * 32 + sub] = o;
    }
}

// ---------------- pooling: pooled[batch[n]] += x[n], batch sorted ----------------
__global__ __launch_bounds__(256) void pool_kernel(const unsigned short* __restrict__ x,
                                                   const int* __restrict__ batch,
                                                   float* __restrict__ pooled) {
    const int lane = threadIdx.x & 63, wid = threadIdx.x >> 6;
    const int base = (blockIdx.x * 4 + wid) * 8;
    float4 acc = make_float4(0.f, 0.f, 0.f, 0.f);
    int gcur = -1;
    for (int i = 0; i < 8; ++i) {
        int n = base + i;
        if (n >= NNODE) break;
        int g = batch[n];
        if (g != gcur) {
            if (gcur >= 0) {
                float* pp = pooled + (size_t)gcur * DD + lane * 4;
                unsafeAtomicAdd(pp + 0, acc.x);
                unsafeAtomicAdd(pp + 1, acc.y);
                unsafeAtomicAdd(pp + 2, acc.z);
                unsafeAtomicAdd(pp + 3, acc.w);
            }
            gcur = g;
            acc = make_float4(0.f, 0.f, 0.f, 0.f);
        }
        ushort4 xv = ((const ushort4*)x)[(size_t)n * 64 + lane];
        acc.x += bf2f(xv.x); acc.y += bf2f(xv.y);
        acc.z += bf2f(xv.z); acc.w += bf2f(xv.w);
    }
    if (gcur >= 0) {
        float* pp = pooled + (size_t)gcur * DD + lane * 4;
        unsafeAtomicAdd(pp + 0, acc.x);
        unsafeAtomicAdd(pp + 1, acc.y);
        unsafeAtomicAdd(pp + 2, acc.z);
        unsafeAtomicAdd(pp + 3, acc.w);
    }
}

// ---------------- out: d_out = pooled @ outW + outb ----------------
__global__ __launch_bounds__(64) void out_kernel(const float* __restrict__ pooled,
                                                 const float* __restrict__ outW,
                                                 const float* __restrict__ outb,
                                                 float* __restrict__ out) {
    const int g = blockIdx.x, lane = threadIdx.x;
    float4 p = ((const float4*)pooled)[g * 64 + lane];
    float s[6];
    #pragma unroll
    for (int j = 0; j < 6; ++j) {
        float a = p.x * outW[(lane * 4 + 0) * 6 + j] + p.y * outW[(lane * 4 + 1) * 6 + j] +
                  p.z * outW[(lane * 4 + 2) * 6 + j] + p.w * outW[(lane * 4 + 3) * 6 + j];
        #pragma unroll
        for (int off = 32; off; off >>= 1) a += __shfl_down(a, off);
        s[j] = a;
    }
    if (lane == 0) {
        #pragma unroll
        for (int j = 0; j < 6; ++j) out[g * 6 + j] = s[j] + outb[j];
    }
}

extern "C" void kernel_launch(void* const* d_in, const int* in_sizes, int n_in,
                              void* d_out, int out_size, void* d_ws, size_t ws_size,
                              hipStream_t stream) {
    const float* nf    = (const float*)d_in[0];
    const int*   ei    = (const int*)d_in[1];
    const float* aw    = (const float*)d_in[2];
    const int*   batch = (const int*)d_in[3];
    const float* aW    = (const float*)d_in[4];
    const float* ab    = (const float*)d_in[5];
    const float* eW    = (const float*)d_in[6];
    const float* eb    = (const float*)d_in[7];
    const float* mlpW  = (const float*)d_in[8];
    const float* mlpb  = (const float*)d_in[9];
    const float* nnW   = (const float*)d_in[10];
    const float* nnb   = (const float*)d_in[11];
    const float* bn_g  = (const float*)d_in[12];
    const float* bn_b  = (const float*)d_in[13];
    const float* bn_m  = (const float*)d_in[14];
    const float* bn_v  = (const float*)d_in[15];
    const float* outW  = (const float*)d_in[16];
    const float* outb  = (const float*)d_in[17];
    float* out = (float*)d_out;

    char* ws = (char*)d_ws;
    size_t off = 0;
    auto alloc = [&](size_t bytes) -> void* {
        void* p = ws + off;
        off += (bytes + 255) & ~(size_t)255;
        return p;
    };
    unsigned short* x    = (unsigned short*)alloc((size_t)MPAD * DD * 2);
    unsigned short* P    = (unsigned short*)alloc((size_t)MPAD * DD * 2);
    unsigned short* Q    = (unsigned short*)alloc((size_t)MPAD * DD * 2);
    unsigned short* aggB = (unsigned short*)alloc((size_t)MPAD * DD * 2);
    unsigned short* nfb  = (unsigned short*)alloc((size_t)MPAD * 96 * 2);
    unsigned short* wc1  = (unsigned short*)alloc(256 * 512 * 2);
    unsigned short* wc2  = (unsigned short*)alloc(256 * 512 * 2);
    unsigned short* nnt  = (unsigned short*)alloc(256 * 256 * 2);
    unsigned short* aWt  = (unsigned short*)alloc(256 * 96 * 2);
    float* u_all = (float*)alloc(4 * DD * 4);
    float* v_all = (float*)alloc(4 * DD * 4);
    float* scale = (float*)alloc(DD * 4);
    float* shift = (float*)alloc(DD * 4);
    float* pooled = (float*)alloc((size_t)NGRAPH * DD * 4);
    int* counts  = (int*)alloc((size_t)NNODE * 4);
    int* offsets = (int*)alloc((size_t)NNODE * 4);
    int* cursor  = (int*)alloc((size_t)NNODE * 4);
    int* blockSums = (int*)alloc(NCHUNK * 4);
    int* srowB   = (int*)alloc((size_t)NEDGE * 4);
    float* swB   = (float*)alloc((size_t)NEDGE * 4);
    (void)ws_size; (void)in_sizes; (void)n_in; (void)out_size;

    // one-time prep
    prep_weights<<<512, 256, 0, stream>>>(mlpW, nnW, aW, ab, wc1, wc2, nnt, aWt);
    prep_uv<<<1, 256, 0, stream>>>(eW, eb, mlpW, mlpb, nnb, bn_g, bn_b, bn_m, bn_v,
                                   u_all, v_all, scale, shift);
    nfb_prep<<<(MPAD * 96 + 255) / 256, 256, 0, stream>>>(nf, nfb);
    xinit_gemm<<<MPAD / 128, 512, 0, stream>>>(nfb, aWt, x);

    // CSR build (once; shared by all 4 layers)
    hipMemsetAsync(counts, 0, (size_t)NNODE * 4, stream);
    hist_kernel<<<(NEDGE + 255) / 256, 256, 0, stream>>>(ei, counts);
    scan1<<<NCHUNK, 256, 0, stream>>>(counts, blockSums);
    scan2<<<1, 64, 0, stream>>>(blockSums);
    scan3<<<NCHUNK, 256, 0, stream>>>(counts, blockSums, offsets, cursor);
    scatter_kernel<<<(NEDGE + 255) / 256, 256, 0, stream>>>(ei, aw, cursor, srowB, swB);

    for (int k = 0; k < 4; ++k) {
        int Ktot = k ? 512 : 256;
        gemm_kernel<0><<<MPAD / 128, 512, 0, stream>>>(x, k ? P : nullptr, wc1, 512, Ktot,
                                                       P, nullptr, nullptr);
        gemm_kernel<0><<<MPAD / 128, 512, 0, stream>>>(x, k ? Q : nullptr, wc2, 512, Ktot,
                                                       Q, nullptr, nullptr);
        edge_csr<<<(NNODE + 3) / 4, 256, 0, stream>>>(offsets, counts, srowB, swB, x, P, Q,
                                                      u_all + k * DD, v_all + k * DD, aggB);
        gemm_kernel<1><<<MPAD / 128, 512, 0, stream>>>(aggB, nullptr, nnt, 256, 256,
                                                       x, scale, shift);
    }

    hipMemsetAsync(pooled, 0, (size_t)NGRAPH * DD * 4, stream);
    pool_kernel<<<(NNODE + 31) / 32, 256, 0, stream>>>(x, batch, pooled);
    out_kernel<<<NGRAPH, 64, 0, stream>>>(pooled, outW, outb, out);
}

// Round 5
// 518.151 us; speedup vs baseline: 6.1329x; 1.0028x over previous
//
#include <hip/hip_runtime.h>
#include <stdint.h>

#define DD 256
#define NNODE 60000
#define MPAD 60032            // 469 * 128
#define NEDGE 200000
#define NGRAPH 1500
#define NCHUNK 59             // ceil(60000/1024)

typedef __bf16 bf16x8 __attribute__((ext_vector_type(8)));
typedef float f32x4 __attribute__((ext_vector_type(4)));
typedef unsigned short us8 __attribute__((ext_vector_type(8)));

__device__ __forceinline__ unsigned short f2bf(float f) {
    union { float f; unsigned int u; } v; v.f = f;
    unsigned int r = v.u + 0x7FFFu + ((v.u >> 16) & 1u);
    return (unsigned short)(r >> 16);
}
__device__ __forceinline__ float bf2f(unsigned short h) {
    union { unsigned int u; float f; } v; v.u = ((unsigned int)h) << 16;
    return v.f;
}
__device__ __forceinline__ void gload_lds16(const void* g, void* l) {
    __builtin_amdgcn_global_load_lds((const __attribute__((address_space(1))) void*)g,
                                     (__attribute__((address_space(3))) void*)l, 16, 0, 0);
}

// ---------------- weight prep: transposed bf16 weights ----------------
__global__ __launch_bounds__(256) void prep_weights(const float* __restrict__ mlpW,
                                                    const float* __restrict__ nnW,
                                                    const float* __restrict__ aW,
                                                    const float* __restrict__ ab,
                                                    unsigned short* __restrict__ wc1,
                                                    unsigned short* __restrict__ wc2,
                                                    unsigned short* __restrict__ nnt,
                                                    unsigned short* __restrict__ aWt) {
    int idx = blockIdx.x * 256 + threadIdx.x;
    if (idx < 256 * 512) {
        int n = idx >> 9, k = idx & 511;
        float v1 = (k < 256) ? mlpW[k * DD + n] : mlpW[(k + 256) * DD + n];
        wc1[idx] = f2bf(v1);
        wc2[idx] = f2bf(mlpW[(k + 256) * DD + n]);
    }
    if (idx < 256 * 256) {
        int n = idx >> 8, k = idx & 255;
        nnt[idx] = f2bf(nnW[k * DD + n]);
    }
    if (idx < 256 * 96) {
        int n = idx / 96, k = idx - n * 96;
        float v = (k < 92) ? aW[k * DD + n] : (k == 92 ? ab[n] : 0.0f);
        aWt[idx] = f2bf(v);
    }
}

// ---------------- u/v chains + BN fold ----------------
__global__ __launch_bounds__(256) void prep_uv(const float* __restrict__ eW, const float* __restrict__ eb,
                                               const float* __restrict__ mlpW, const float* __restrict__ mlpb,
                                               const float* __restrict__ nnb,
                                               const float* __restrict__ bn_g, const float* __restrict__ bn_b,
                                               const float* __restrict__ bn_m, const float* __restrict__ bn_v,
                                               float* __restrict__ u_all, float* __restrict__ v_all,
                                               float* __restrict__ scale, float* __restrict__ shift) {
    __shared__ float uc[DD], vc[DD];
    int d = threadIdx.x;
    uc[d] = eW[d];
    vc[d] = eb[d];
    float sc = bn_g[d] * rsqrtf(bn_v[d] + 1e-5f);
    scale[d] = sc;
    shift[d] = (nnb[d] - bn_m[d]) * sc + bn_b[d];
    __syncthreads();
    const float* W3 = mlpW + 2 * DD * DD;
    for (int it = 0; it < 4; ++it) {
        float su = 0.f, sv = 0.f;
        for (int k = 0; k < DD; ++k) {
            float w = W3[k * DD + d];
            su += uc[k] * w;
            sv += vc[k] * w;
        }
        sv += mlpb[d];
        u_all[it * DD + d] = su;
        v_all[it * DD + d] = sv;
        __syncthreads();
        uc[d] = su; vc[d] = sv;
        __syncthreads();
    }
}

// ---------------- nf -> bf16 padded [MPAD][96] with bias column ----------------
__global__ __launch_bounds__(256) void nfb_prep(const float* __restrict__ nf, unsigned short* __restrict__ nfb) {
    int idx = blockIdx.x * 256 + threadIdx.x;
    if (idx >= MPAD * 96) return;
    int r = idx / 96, c = idx - r * 96;
    float v;
    if (r < NNODE && c < 92) v = nf[(size_t)r * 92 + c];
    else v = (c == 92) ? 1.0f : 0.0f;
    nfb[idx] = f2bf(v);
}

// ---------------- xinit GEMM: x[M][256] = nfb[M][96] @ aWt^T, single-stage ----------------
__global__ __launch_bounds__(512) void xinit_gemm(const unsigned short* __restrict__ nfb,
                                                  const unsigned short* __restrict__ aWt,
                                                  unsigned short* __restrict__ x) {
    __shared__ unsigned short As[128][96];
    __shared__ unsigned short Bs[256][96];
    const int tid = threadIdx.x;
    const int lane = tid & 63, wid = tid >> 6;
    const int wr = wid >> 2, wc = wid & 3;
    const int m0 = blockIdx.x * 128;
    const int lr = lane & 15, lq = lane >> 4;

    for (int i = tid; i < 128 * 12; i += 512) {
        int row = i / 12, ch = (i - row * 12) * 8;
        gload_lds16(nfb + (size_t)(m0 + row) * 96 + ch, &As[row][ch]);
    }
    for (int i = tid; i < 256 * 12; i += 512) {
        int row = i / 12, ch = (i - row * 12) * 8;
        gload_lds16(aWt + (size_t)row * 96 + ch, &Bs[row][ch]);
    }
    __syncthreads();

    f32x4 acc[4][4];
    #pragma unroll
    for (int m = 0; m < 4; ++m)
        #pragma unroll
        for (int n = 0; n < 4; ++n) { f32x4 z = {0.f,0.f,0.f,0.f}; acc[m][n] = z; }

    #pragma unroll
    for (int h = 0; h < 3; ++h) {
        bf16x8 af[4], bf[4];
        #pragma unroll
        for (int m = 0; m < 4; ++m)
            af[m] = *reinterpret_cast<const bf16x8*>(&As[wr * 64 + m * 16 + lr][h * 32 + lq * 8]);
        #pragma unroll
        for (int n = 0; n < 4; ++n)
            bf[n] = *reinterpret_cast<const bf16x8*>(&Bs[wc * 64 + n * 16 + lr][h * 32 + lq * 8]);
        #pragma unroll
        for (int m = 0; m < 4; ++m)
            #pragma unroll
            for (int n = 0; n < 4; ++n)
                acc[m][n] = __builtin_amdgcn_mfma_f32_16x16x32_bf16(af[m], bf[n], acc[m][n], 0, 0, 0);
    }

    #pragma unroll
    for (int m = 0; m < 4; ++m) {
        const int rb = m0 + wr * 64 + m * 16 + lq * 4;
        #pragma unroll
        for (int n = 0; n < 4; ++n) {
            const int c = wc * 64 + n * 16 + lr;
            #pragma unroll
            for (int j = 0; j < 4; ++j)
                x[(size_t)(rb + j) * DD + c] = f2bf(acc[m][n][j]);
        }
    }
}

// ---------------- CSR build ----------------
__global__ __launch_bounds__(256) void hist_kernel(const int* __restrict__ ei, int* __restrict__ counts) {
    int e = blockIdx.x * 256 + threadIdx.x;
    if (e < NEDGE) atomicAdd(&counts[ei[NEDGE + e]], 1);
}

__global__ __launch_bounds__(256) void scan1(const int* __restrict__ counts, int* __restrict__ blockSums) {
    int t = threadIdx.x;
    int base = blockIdx.x * 1024 + t * 4;
    int s = 0;
    #pragma unroll
    for (int i = 0; i < 4; ++i) { int idx = base + i; if (idx < NNODE) s += counts[idx]; }
    __shared__ int red[256];
    red[t] = s; __syncthreads();
    for (int d = 128; d; d >>= 1) { if (t < d) red[t] += red[t + d]; __syncthreads(); }
    if (t == 0) blockSums[blockIdx.x] = red[0];
}

__global__ __launch_bounds__(64) void scan2(int* __restrict__ blockSums) {
    int t = threadIdx.x;
    int v = (t < NCHUNK) ? blockSums[t] : 0;
    int orig = v;
    #pragma unroll
    for (int d = 1; d < 64; d <<= 1) {
        int o = __shfl_up(v, d);
        if (t >= d) v += o;
    }
    if (t < NCHUNK) blockSums[t] = v - orig;   // exclusive
}

__global__ __launch_bounds__(256) void scan3(const int* __restrict__ counts, const int* __restrict__ blockSums,
                                             int* __restrict__ offsets, int* __restrict__ cursor) {
    int t = threadIdx.x;
    int base = blockIdx.x * 1024 + t * 4;
    int c[4]; int s = 0;
    #pragma unroll
    for (int i = 0; i < 4; ++i) { int idx = base + i; c[i] = (idx < NNODE) ? counts[idx] : 0; s += c[i]; }
    __shared__ int lds[256];
    lds[t] = s; __syncthreads();
    for (int d = 1; d < 256; d <<= 1) {
        int v = (t >= d) ? lds[t - d] : 0;
        __syncthreads();
        lds[t] += v;
        __syncthreads();
    }
    int off = blockSums[blockIdx.x] + lds[t] - s;
    #pragma unroll
    for (int i = 0; i < 4; ++i) {
        int idx = base + i;
        if (idx < NNODE) { offsets[idx] = off; cursor[idx] = off; off += c[i]; }
    }
}

__global__ __launch_bounds__(256) void scatter_kernel(const int* __restrict__ ei, const float* __restrict__ aw,
                                                      int* __restrict__ cursor,
                                                      int* __restrict__ srow, float* __restrict__ sw) {
    int e = blockIdx.x * 256 + threadIdx.x;
    if (e < NEDGE) {
        int c = ei[NEDGE + e];
        int pos = atomicAdd(&cursor[c], 1);
        srow[pos] = ei[e];
        sw[pos] = aw[e];
    }
}

// ---------------- merged P/Q GEMM, swizzled LDS, 48 KB ----------------
// Twin mapping: bids 16p+{0..7} = P-half, 16p+{8..15} = Q-half of the SAME 8
// M-blocks; twins are congruent mod 8 -> same XCD under round-robin -> the
// Q-twin's x A-tile reads hit L2.
// P-half: C = [x|P]@wc1^T ; writes P = C and PX = C + x (edge operand).
// Q-half: C = [x|Qv]@wc2^T ; writes Qv = C + cq[c]  (cq = v1 at layer0, mlpb after).
__global__ __launch_bounds__(512) void gemm_pq(const unsigned short* __restrict__ X,
                                               const unsigned short* __restrict__ Pst,
                                               const unsigned short* __restrict__ Qst,
                                               const unsigned short* __restrict__ B1,
                                               const unsigned short* __restrict__ B2,
                                               unsigned short* __restrict__ Pout,
                                               unsigned short* __restrict__ PXout,
                                               unsigned short* __restrict__ Qout,
                                               const float* __restrict__ cq,
                                               int Ktot) {
    __shared__ unsigned short As[128][64];
    __shared__ unsigned short Bs[256][64];
    const int b = blockIdx.x;
    const int pairb = b >> 4, jj = b & 15;
    const int sel = jj >> 3, sub = jj & 7;
    const int mb = pairb * 8 + sub;
    if (mb >= MPAD / 128) return;
    const int m0 = mb * 128;

    const unsigned short* A1 = sel ? Qst : Pst;
    const unsigned short* Bt = sel ? B2 : B1;

    const int tid = threadIdx.x;
    const int lane = tid & 63, wid = tid >> 6;
    const int wr = wid >> 2, wc = wid & 3;
    const int lr = lane & 15, lq = lane >> 4;
    const int srow = tid >> 3;
    const int jphys = tid & 7;
    const int jlog = jphys ^ (srow & 7);
    const int scol_g = jlog * 8;
    const int scol_l = jphys * 8;
    const int xorj = (lr & 7);

    f32x4 acc[4][4];
    #pragma unroll
    for (int m = 0; m < 4; ++m)
        #pragma unroll
        for (int n = 0; n < 4; ++n) { f32x4 z = {0.f,0.f,0.f,0.f}; acc[m][n] = z; }

    const int nk = Ktot >> 6;
    for (int kt = 0; kt < nk; ++kt) {
        const int k0 = kt << 6;
        const unsigned short* Ap; int ka;
        if (k0 < 256) { Ap = X; ka = k0; } else { Ap = A1; ka = k0 - 256; }
        #pragma unroll
        for (int p = 0; p < 2; ++p) {
            int row = p * 64 + srow;
            gload_lds16(Ap + (size_t)(m0 + row) * DD + ka + scol_g, &As[row][scol_l]);
        }
        #pragma unroll
        for (int p = 0; p < 4; ++p) {
            int row = p * 64 + srow;
            gload_lds16(Bt + (size_t)row * 512 + k0 + scol_g, &Bs[row][scol_l]);
        }
        __syncthreads();
        #pragma unroll
        for (int h = 0; h < 2; ++h) {
            const int jp = ((h * 4 + lq) ^ xorj) * 8;
            bf16x8 af[4], bfr[4];
            #pragma unroll
            for (int m = 0; m < 4; ++m)
                af[m] = *reinterpret_cast<const bf16x8*>(&As[wr * 64 + m * 16 + lr][jp]);
            #pragma unroll
            for (int n = 0; n < 4; ++n)
                bfr[n] = *reinterpret_cast<const bf16x8*>(&Bs[wc * 64 + n * 16 + lr][jp]);
            #pragma unroll
            for (int m = 0; m < 4; ++m)
                #pragma unroll
                for (int n = 0; n < 4; ++n)
                    acc[m][n] = __builtin_amdgcn_mfma_f32_16x16x32_bf16(af[m], bfr[n], acc[m][n], 0, 0, 0);
        }
        __syncthreads();
    }

    #pragma unroll
    for (int m = 0; m < 4; ++m) {
        const int rb = m0 + wr * 64 + m * 16 + lq * 4;
        #pragma unroll
        for (int n = 0; n < 4; ++n) {
            const int c = wc * 64 + n * 16 + lr;
            if (sel == 0) {
                #pragma unroll
                for (int j = 0; j < 4; ++j) {
                    const size_t idx = (size_t)(rb + j) * DD + c;
                    float cv = acc[m][n][j];
                    Pout[idx] = f2bf(cv);
                    PXout[idx] = f2bf(cv + bf2f(X[idx]));
                }
            } else {
                const float cqc = cq[c];
                #pragma unroll
                for (int j = 0; j < 4; ++j) {
                    const size_t idx = (size_t)(rb + j) * DD + c;
                    Qout[idx] = f2bf(acc[m][n][j] + cqc);
                }
            }
        }
    }
}

// ---------------- BN GEMM: x = relu((aggB @ nnt^T) * scale + shift) ----------------
__global__ __launch_bounds__(512) void gemm_bn(const unsigned short* __restrict__ A,
                                               const unsigned short* __restrict__ Bt,
                                               unsigned short* __restrict__ Cout,
                                               const float* __restrict__ scale,
                                               const float* __restrict__ shift) {
    __shared__ unsigned short As[128][64];
    __shared__ unsigned short Bs[256][64];
    const int tid = threadIdx.x;
    const int lane = tid & 63, wid = tid >> 6;
    const int wr = wid >> 2, wc = wid & 3;
    const int m0 = blockIdx.x * 128;
    const int lr = lane & 15, lq = lane >> 4;
    const int srow = tid >> 3;
    const int jphys = tid & 7;
    const int jlog = jphys ^ (srow & 7);
    const int scol_g = jlog * 8;
    const int scol_l = jphys * 8;
    const int xorj = (lr & 7);

    f32x4 acc[4][4];
    #pragma unroll
    for (int m = 0; m < 4; ++m)
        #pragma unroll
        for (int n = 0; n < 4; ++n) { f32x4 z = {0.f,0.f,0.f,0.f}; acc[m][n] = z; }

    for (int kt = 0; kt < 4; ++kt) {
        const int k0 = kt << 6;
        #pragma unroll
        for (int p = 0; p < 2; ++p) {
            int row = p * 64 + srow;
            gload_lds16(A + (size_t)(m0 + row) * DD + k0 + scol_g, &As[row][scol_l]);
        }
        #pragma unroll
        for (int p = 0; p < 4; ++p) {
            int row = p * 64 + srow;
            gload_lds16(Bt + (size_t)row * DD + k0 + scol_g, &Bs[row][scol_l]);
        }
        __syncthreads();
        #pragma unroll
        for (int h = 0; h < 2; ++h) {
            const int jp = ((h * 4 + lq) ^ xorj) * 8;
            bf16x8 af[4], bfr[4];
            #pragma unroll
            for (int m = 0; m < 4; ++m)
                af[m] = *reinterpret_cast<const bf16x8*>(&As[wr * 64 + m * 16 + lr][jp]);
            #pragma unroll
            for (int n = 0; n < 4; ++n)
                bfr[n] = *reinterpret_cast<const bf16x8*>(&Bs[wc * 64 + n * 16 + lr][jp]);
            #pragma unroll
            for (int m = 0; m < 4; ++m)
                #pragma unroll
                for (int n = 0; n < 4; ++n)
                    acc[m][n] = __builtin_amdgcn_mfma_f32_16x16x32_bf16(af[m], bfr[n], acc[m][n], 0, 0, 0);
        }
        __syncthreads();
    }

    #pragma unroll
    for (int m = 0; m < 4; ++m) {
        const int rb = m0 + wr * 64 + m * 16 + lq * 4;
        #pragma unroll
        for (int n = 0; n < 4; ++n) {
            const int c = wc * 64 + n * 16 + lr;
            #pragma unroll
            for (int j = 0; j < 4; ++j) {
                const size_t idx = (size_t)(rb + j) * DD + c;
                float y = fmaxf(acc[m][n][j] * scale[c] + shift[c], 0.f);
                Cout[idx] = f2bf(y);
            }
        }
    }
}

// ---------------- edge pass (CSR gather, single-gather): one wave per node ----------------
// aggB[n] = x[n] + sum_{e: col(e)=n} relu( PX[r] + Qv[n] + w*u )
__global__ __launch_bounds__(256) void edge_csr(const int* __restrict__ offsets, const int* __restrict__ counts,
                                                const int* __restrict__ srow, const float* __restrict__ sw,
                                                const unsigned short* __restrict__ X,
                                                const unsigned short* __restrict__ PX,
                                                const unsigned short* __restrict__ Qv,
                                                const float* __restrict__ u,
                                                unsigned short* __restrict__ aggB) {
    const int lane = threadIdx.x & 63, wid = threadIdx.x >> 6;
    const int n = blockIdx.x * 4 + wid;
    if (n >= NNODE) return;
    const int start = offsets[n];
    const int deg = counts[n];
    const int sub = lane & 31, h = lane >> 5;

    const us8* PX8 = (const us8*)PX;

    float4 u0 = ((const float4*)u)[sub * 2], u1 = ((const float4*)u)[sub * 2 + 1];
    float uu[8] = {u0.x, u0.y, u0.z, u0.w, u1.x, u1.y, u1.z, u1.w};

    us8 qv = ((const us8*)Qv)[(size_t)n * 32 + sub];
    float qb[8];
    #pragma unroll
    for (int c = 0; c < 8; ++c) qb[c] = bf2f(qv[c]);

    float a[8];
    us8 xv = ((const us8*)X)[(size_t)n * 32 + sub];
    #pragma unroll
    for (int c = 0; c < 8; ++c) a[c] = (h == 0) ? bf2f(xv[c]) : 0.f;

    for (int b0 = 0; b0 < deg; b0 += 64) {
        int m = deg - b0; if (m > 64) m = 64;
        int myr = 0; float myw = 0.f;
        if (lane < m) { myr = srow[start + b0 + lane]; myw = sw[start + b0 + lane]; }
        int iters = (m + 1) >> 1;
        for (int j = 0; j < iters; ++j) {
            int el = 2 * j + h;
            int r = __shfl(myr, el);
            float w = __shfl(myw, el);
            if (el < m) {
                us8 p2 = PX8[(size_t)r * 32 + sub];
                #pragma unroll
                for (int c = 0; c < 8; ++c)
                    a[c] += fmaxf(bf2f(p2[c]) + qb[c] + w * uu[c], 0.f);
            }
        }
    }
    #pragma unroll
    for (int c = 0; c < 8; ++c) a[c] += __shfl_xor(a[c], 32);
    if (h == 0) {
        us8 o;
        #pragma unroll
        for (int c = 0; c < 8; ++c) o[c] = f2bf(a[c]);
        ((us8*)aggB)[(size_t)n * 32 + sub] = o;
    }
}

// ---------------- pooling: pooled[batch[n]] += x[n], batch sorted ----------------
__global__ __launch_bounds__(256) void pool_kernel(const unsigned short* __restrict__ x,
                                                   const int* __restrict__ batch,
                                                   float* __restrict__ pooled) {
    const int lane = threadIdx.x & 63, wid = threadIdx.x >> 6;
    const int base = (blockIdx.x * 4 + wid) * 8;
    float4 acc = make_float4(0.f, 0.f, 0.f, 0.f);
    int gcur = -1;
    for (int i = 0; i < 8; ++i) {
        int n = base + i;
        if (n >= NNODE) break;
        int g = batch[n];
        if (g != gcur) {
            if (gcur >= 0) {
                float* pp = pooled + (size_t)gcur * DD + lane * 4;
                unsafeAtomicAdd(pp + 0, acc.x);
                unsafeAtomicAdd(pp + 1, acc.y);
                unsafeAtomicAdd(pp + 2, acc.z);
                unsafeAtomicAdd(pp + 3, acc.w);
            }
            gcur = g;
            acc = make_float4(0.f, 0.f, 0.f, 0.f);
        }
        ushort4 xv = ((const ushort4*)x)[(size_t)n * 64 + lane];
        acc.x += bf2f(xv.x); acc.y += bf2f(xv.y);
        acc.z += bf2f(xv.z); acc.w += bf2f(xv.w);
    }
    if (gcur >= 0) {
        float* pp = pooled + (size_t)gcur * DD + lane * 4;
        unsafeAtomicAdd(pp + 0, acc.x);
        unsafeAtomicAdd(pp + 1, acc.y);
        unsafeAtomicAdd(pp + 2, acc.z);
        unsafeAtomicAdd(pp + 3, acc.w);
    }
}

// ---------------- out: d_out = pooled @ outW + outb ----------------
__global__ __launch_bounds__(64) void out_kernel(const float* __restrict__ pooled,
                                                 const float* __restrict__ outW,
                                                 const float* __restrict__ outb,
                                                 float* __restrict__ out) {
    const int g = blockIdx.x, lane = threadIdx.x;
    float4 p = ((const float4*)pooled)[g * 64 + lane];
    float s[6];
    #pragma unroll
    for (int j = 0; j < 6; ++j) {
        float a = p.x * outW[(lane * 4 + 0) * 6 + j] + p.y * outW[(lane * 4 + 1) * 6 + j] +
                  p.z * outW[(lane * 4 + 2) * 6 + j] + p.w * outW[(lane * 4 + 3) * 6 + j];
        #pragma unroll
        for (int off = 32; off; off >>= 1) a += __shfl_down(a, off);
        s[j] = a;
    }
    if (lane == 0) {
        #pragma unroll
        for (int j = 0; j < 6; ++j) out[g * 6 + j] = s[j] + outb[j];
    }
}

extern "C" void kernel_launch(void* const* d_in, const int* in_sizes, int n_in,
                              void* d_out, int out_size, void* d_ws, size_t ws_size,
                              hipStream_t stream) {
    const float* nf    = (const float*)d_in[0];
    const int*   ei    = (const int*)d_in[1];
    const float* aw    = (const float*)d_in[2];
    const int*   batch = (const int*)d_in[3];
    const float* aW    = (const float*)d_in[4];
    const float* ab    = (const float*)d_in[5];
    const float* eW    = (const float*)d_in[6];
    const float* eb    = (const float*)d_in[7];
    const float* mlpW  = (const float*)d_in[8];
    const float* mlpb  = (const float*)d_in[9];
    const float* nnW   = (const float*)d_in[10];
    const float* nnb   = (const float*)d_in[11];
    const float* bn_g  = (const float*)d_in[12];
    const float* bn_b  = (const float*)d_in[13];
    const float* bn_m  = (const float*)d_in[14];
    const float* bn_v  = (const float*)d_in[15];
    const float* outW  = (const float*)d_in[16];
    const float* outb  = (const float*)d_in[17];
    float* out = (float*)d_out;

    char* ws = (char*)d_ws;
    size_t off = 0;
    auto alloc = [&](size_t bytes) -> void* {
        void* p = ws + off;
        off += (bytes + 255) & ~(size_t)255;
        return p;
    };
    unsigned short* x    = (unsigned short*)alloc((size_t)MPAD * DD * 2);
    unsigned short* P    = (unsigned short*)alloc((size_t)MPAD * DD * 2);
    unsigned short* Qv   = (unsigned short*)alloc((size_t)MPAD * DD * 2);
    unsigned short* aggB = (unsigned short*)alloc((size_t)MPAD * DD * 2);
    // PX shares its region with nfb (nfb dead after xinit; PX written from layer 0 on)
    unsigned short* PX   = (unsigned short*)alloc((size_t)MPAD * DD * 2);
    unsigned short* nfb  = PX;   // MPAD*96*2 < MPAD*DD*2, alias is safe
    unsigned short* wc1  = (unsigned short*)alloc(256 * 512 * 2);
    unsigned short* wc2  = (unsigned short*)alloc(256 * 512 * 2);
    unsigned short* nnt  = (unsigned short*)alloc(256 * 256 * 2);
    unsigned short* aWt  = (unsigned short*)alloc(256 * 96 * 2);
    float* u_all = (float*)alloc(4 * DD * 4);
    float* v_all = (float*)alloc(4 * DD * 4);
    float* scale = (float*)alloc(DD * 4);
    float* shift = (float*)alloc(DD * 4);
    float* pooled = (float*)alloc((size_t)NGRAPH * DD * 4);
    int* counts  = (int*)alloc((size_t)NNODE * 4);
    int* offsets = (int*)alloc((size_t)NNODE * 4);
    int* cursor  = (int*)alloc((size_t)NNODE * 4);
    int* blockSums = (int*)alloc(NCHUNK * 4);
    int* srowB   = (int*)alloc((size_t)NEDGE * 4);
    float* swB   = (float*)alloc((size_t)NEDGE * 4);
    (void)ws_size; (void)in_sizes; (void)n_in; (void)out_size;

    // one-time prep
    prep_weights<<<512, 256, 0, stream>>>(mlpW, nnW, aW, ab, wc1, wc2, nnt, aWt);
    prep_uv<<<1, 256, 0, stream>>>(eW, eb, mlpW, mlpb, nnb, bn_g, bn_b, bn_m, bn_v,
                                   u_all, v_all, scale, shift);
    nfb_prep<<<(MPAD * 96 + 255) / 256, 256, 0, stream>>>(nf, nfb);
    xinit_gemm<<<MPAD / 128, 512, 0, stream>>>(nfb, aWt, x);

    // CSR build (once; shared by all 4 layers)
    hipMemsetAsync(counts, 0, (size_t)NNODE * 4, stream);
    hist_kernel<<<(NEDGE + 255) / 256, 256, 0, stream>>>(ei, counts);
    scan1<<<NCHUNK, 256, 0, stream>>>(counts, blockSums);
    scan2<<<1, 64, 0, stream>>>(blockSums);
    scan3<<<NCHUNK, 256, 0, stream>>>(counts, blockSums, offsets, cursor);
    scatter_kernel<<<(NEDGE + 255) / 256, 256, 0, stream>>>(ei, aw, cursor, srowB, swB);

    const int npairs = (MPAD / 128 + 7) / 8;   // 59
    for (int k = 0; k < 4; ++k) {
        gemm_pq<<<npairs * 16, 512, 0, stream>>>(x, P, Qv, wc1, wc2, P, PX, Qv,
                                                 k == 0 ? v_all : mlpb, k ? 512 : 256);
        edge_csr<<<(NNODE + 3) / 4, 256, 0, stream>>>(offsets, counts, srowB, swB, x, PX, Qv,
                                                      u_all + k * DD, aggB);
        gemm_bn<<<MPAD / 128, 512, 0, stream>>>(aggB, nnt, x, scale, shift);
    }

    hipMemsetAsync(pooled, 0, (size_t)NGRAPH * DD * 4, stream);
    pool_kernel<<<(NNODE + 31) / 32, 256, 0, stream>>>(x, batch, pooled);
    out_kernel<<<NGRAPH, 64, 0, stream>>>(pooled, outW, outb, out);
}

// Round 6
// 511.014 us; speedup vs baseline: 6.2185x; 1.0140x over previous
//
#include <hip/hip_runtime.h>
#include <stdint.h>

#define DD 256
#define NNODE 60000
#define MPAD 60032            // 469 * 128
#define NEDGE 200000
#define NGRAPH 1500
#define NCHUNK 59             // ceil(60000/1024)

typedef __bf16 bf16x8 __attribute__((ext_vector_type(8)));
typedef float f32x4 __attribute__((ext_vector_type(4)));
typedef unsigned short us8 __attribute__((ext_vector_type(8)));

__device__ __forceinline__ unsigned short f2bf(float f) {
    union { float f; unsigned int u; } v; v.f = f;
    unsigned int r = v.u + 0x7FFFu + ((v.u >> 16) & 1u);
    return (unsigned short)(r >> 16);
}
__device__ __forceinline__ float bf2f(unsigned short h) {
    union { unsigned int u; float f; } v; v.u = ((unsigned int)h) << 16;
    return v.f;
}
__device__ __forceinline__ void gload_lds16(const void* g, void* l) {
    __builtin_amdgcn_global_load_lds((const __attribute__((address_space(1))) void*)g,
                                     (__attribute__((address_space(3))) void*)l, 16, 0, 0);
}

// ---------------- weight prep: transposed bf16 weights ----------------
__global__ __launch_bounds__(256) void prep_weights(const float* __restrict__ mlpW,
                                                    const float* __restrict__ nnW,
                                                    const float* __restrict__ aW,
                                                    const float* __restrict__ ab,
                                                    unsigned short* __restrict__ wc1,
                                                    unsigned short* __restrict__ wc2,
                                                    unsigned short* __restrict__ nnt,
                                                    unsigned short* __restrict__ aWt) {
    int idx = blockIdx.x * 256 + threadIdx.x;
    if (idx < 256 * 512) {
        int n = idx >> 9, k = idx & 511;
        float v1 = (k < 256) ? mlpW[k * DD + n] : mlpW[(k + 256) * DD + n];
        wc1[idx] = f2bf(v1);
        wc2[idx] = f2bf(mlpW[(k + 256) * DD + n]);
    }
    if (idx < 256 * 256) {
        int n = idx >> 8, k = idx & 255;
        nnt[idx] = f2bf(nnW[k * DD + n]);
    }
    if (idx < 256 * 96) {
        int n = idx / 96, k = idx - n * 96;
        float v = (k < 92) ? aW[k * DD + n] : (k == 92 ? ab[n] : 0.0f);
        aWt[idx] = f2bf(v);
    }
}

// ---------------- u/v chains + BN fold ----------------
__global__ __launch_bounds__(256) void prep_uv(const float* __restrict__ eW, const float* __restrict__ eb,
                                               const float* __restrict__ mlpW, const float* __restrict__ mlpb,
                                               const float* __restrict__ nnb,
                                               const float* __restrict__ bn_g, const float* __restrict__ bn_b,
                                               const float* __restrict__ bn_m, const float* __restrict__ bn_v,
                                               float* __restrict__ u_all, float* __restrict__ v_all,
                                               float* __restrict__ scale, float* __restrict__ shift) {
    __shared__ float uc[DD], vc[DD];
    int d = threadIdx.x;
    uc[d] = eW[d];
    vc[d] = eb[d];
    float sc = bn_g[d] * rsqrtf(bn_v[d] + 1e-5f);
    scale[d] = sc;
    shift[d] = (nnb[d] - bn_m[d]) * sc + bn_b[d];
    __syncthreads();
    const float* W3 = mlpW + 2 * DD * DD;
    for (int it = 0; it < 4; ++it) {
        float su = 0.f, sv = 0.f;
        for (int k = 0; k < DD; ++k) {
            float w = W3[k * DD + d];
            su += uc[k] * w;
            sv += vc[k] * w;
        }
        sv += mlpb[d];
        u_all[it * DD + d] = su;
        v_all[it * DD + d] = sv;
        __syncthreads();
        uc[d] = su; vc[d] = sv;
        __syncthreads();
    }
}

// ---------------- nf -> bf16 padded [MPAD][96] with bias column ----------------
__global__ __launch_bounds__(256) void nfb_prep(const float* __restrict__ nf, unsigned short* __restrict__ nfb) {
    int idx = blockIdx.x * 256 + threadIdx.x;
    if (idx >= MPAD * 96) return;
    int r = idx / 96, c = idx - r * 96;
    float v;
    if (r < NNODE && c < 92) v = nf[(size_t)r * 92 + c];
    else v = (c == 92) ? 1.0f : 0.0f;
    nfb[idx] = f2bf(v);
}

// ---------------- xinit GEMM: x[M][256] = nfb[M][96] @ aWt^T, single-stage ----------------
__global__ __launch_bounds__(512) void xinit_gemm(const unsigned short* __restrict__ nfb,
                                                  const unsigned short* __restrict__ aWt,
                                                  unsigned short* __restrict__ x) {
    __shared__ unsigned short shmem[(128 + 256) * 96];
    unsigned short (*As)[96] = (unsigned short(*)[96])shmem;
    unsigned short (*Bs)[96] = (unsigned short(*)[96])(shmem + 128 * 96);
    const int tid = threadIdx.x;
    const int lane = tid & 63, wid = tid >> 6;
    const int wr = wid >> 2, wc = wid & 3;
    const int m0 = blockIdx.x * 128;
    const int lr = lane & 15, lq = lane >> 4;

    for (int i = tid; i < 128 * 12; i += 512) {
        int row = i / 12, ch = (i - row * 12) * 8;
        gload_lds16(nfb + (size_t)(m0 + row) * 96 + ch, &As[row][ch]);
    }
    for (int i = tid; i < 256 * 12; i += 512) {
        int row = i / 12, ch = (i - row * 12) * 8;
        gload_lds16(aWt + (size_t)row * 96 + ch, &Bs[row][ch]);
    }
    __syncthreads();

    f32x4 acc[4][4];
    #pragma unroll
    for (int m = 0; m < 4; ++m)
        #pragma unroll
        for (int n = 0; n < 4; ++n) { f32x4 z = {0.f,0.f,0.f,0.f}; acc[m][n] = z; }

    #pragma unroll
    for (int h = 0; h < 3; ++h) {
        bf16x8 af[4], bf[4];
        #pragma unroll
        for (int m = 0; m < 4; ++m)
            af[m] = *reinterpret_cast<const bf16x8*>(&As[wr * 64 + m * 16 + lr][h * 32 + lq * 8]);
        #pragma unroll
        for (int n = 0; n < 4; ++n)
            bf[n] = *reinterpret_cast<const bf16x8*>(&Bs[wc * 64 + n * 16 + lr][h * 32 + lq * 8]);
        #pragma unroll
        for (int m = 0; m < 4; ++m)
            #pragma unroll
            for (int n = 0; n < 4; ++n)
                acc[m][n] = __builtin_amdgcn_mfma_f32_16x16x32_bf16(af[m], bf[n], acc[m][n], 0, 0, 0);
    }
    __syncthreads();

    // LDS-staged coalesced epilogue
    unsigned short* stg = shmem;
    #pragma unroll
    for (int half = 0; half < 2; ++half) {
        if (wr == half) {
            #pragma unroll
            for (int m = 0; m < 4; ++m)
                #pragma unroll
                for (int n = 0; n < 4; ++n) {
                    const int cs = (wc * 64 + n * 16 + lr) ^ (lq << 4);
                    #pragma unroll
                    for (int j = 0; j < 4; ++j)
                        stg[(m * 16 + lq * 4 + j) * 256 + cs] = f2bf(acc[m][n][j]);
                }
        }
        __syncthreads();
        const int rbase = m0 + half * 64;
        #pragma unroll
        for (int t = 0; t < 4; ++t) {
            int tt = tid + t * 512;
            int rl = tt >> 5, ch = tt & 31;
            int chs = ch ^ (((rl >> 2) & 3) << 1);
            us8 pv = *(const us8*)&stg[rl * 256 + chs * 8];
            ((us8*)x)[(size_t)(rbase + rl) * 32 + ch] = pv;
        }
        __syncthreads();
    }
}

// ---------------- CSR build ----------------
__global__ __launch_bounds__(256) void hist_kernel(const int* __restrict__ ei, int* __restrict__ counts) {
    int e = blockIdx.x * 256 + threadIdx.x;
    if (e < NEDGE) atomicAdd(&counts[ei[NEDGE + e]], 1);
}

__global__ __launch_bounds__(256) void scan1(const int* __restrict__ counts, int* __restrict__ blockSums) {
    int t = threadIdx.x;
    int base = blockIdx.x * 1024 + t * 4;
    int s = 0;
    #pragma unroll
    for (int i = 0; i < 4; ++i) { int idx = base + i; if (idx < NNODE) s += counts[idx]; }
    __shared__ int red[256];
    red[t] = s; __syncthreads();
    for (int d = 128; d; d >>= 1) { if (t < d) red[t] += red[t + d]; __syncthreads(); }
    if (t == 0) blockSums[blockIdx.x] = red[0];
}

__global__ __launch_bounds__(64) void scan2(int* __restrict__ blockSums) {
    int t = threadIdx.x;
    int v = (t < NCHUNK) ? blockSums[t] : 0;
    int orig = v;
    #pragma unroll
    for (int d = 1; d < 64; d <<= 1) {
        int o = __shfl_up(v, d);
        if (t >= d) v += o;
    }
    if (t < NCHUNK) blockSums[t] = v - orig;   // exclusive
}

__global__ __launch_bounds__(256) void scan3(const int* __restrict__ counts, const int* __restrict__ blockSums,
                                             int* __restrict__ offsets, int* __restrict__ cursor) {
    int t = threadIdx.x;
    int base = blockIdx.x * 1024 + t * 4;
    int c[4]; int s = 0;
    #pragma unroll
    for (int i = 0; i < 4; ++i) { int idx = base + i; c[i] = (idx < NNODE) ? counts[idx] : 0; s += c[i]; }
    __shared__ int lds[256];
    lds[t] = s; __syncthreads();
    for (int d = 1; d < 256; d <<= 1) {
        int v = (t >= d) ? lds[t - d] : 0;
        __syncthreads();
        lds[t] += v;
        __syncthreads();
    }
    int off = blockSums[blockIdx.x] + lds[t] - s;
    #pragma unroll
    for (int i = 0; i < 4; ++i) {
        int idx = base + i;
        if (idx < NNODE) { offsets[idx] = off; cursor[idx] = off; off += c[i]; }
    }
}

__global__ __launch_bounds__(256) void scatter_kernel(const int* __restrict__ ei, const float* __restrict__ aw,
                                                      int* __restrict__ cursor,
                                                      int* __restrict__ srow, float* __restrict__ sw) {
    int e = blockIdx.x * 256 + threadIdx.x;
    if (e < NEDGE) {
        int c = ei[NEDGE + e];
        int pos = atomicAdd(&cursor[c], 1);
        srow[pos] = ei[e];
        sw[pos] = aw[e];
    }
}

// ---------------- merged P/Q GEMM, swizzled LDS, 48 KB, LDS-staged epilogue ----------------
// Twin mapping: bids 16p+{0..7} = P-half, 16p+{8..15} = Q-half of the SAME 8
// M-blocks (same XCD under round-robin -> Q-twin's x reads hit L2).
// P-half: C = [x|P]@wc1^T ; writes P = C and PX = C + x (edge operand).
// Q-half: C = [x|Qv]@wc2^T ; writes Qv = C + cq[c]  (cq = v1 at layer0, mlpb after).
__global__ __launch_bounds__(512) void gemm_pq(const unsigned short* __restrict__ X,
                                               const unsigned short* __restrict__ Pst,
                                               const unsigned short* __restrict__ Qst,
                                               const unsigned short* __restrict__ B1,
                                               const unsigned short* __restrict__ B2,
                                               unsigned short* __restrict__ Pout,
                                               unsigned short* __restrict__ PXout,
                                               unsigned short* __restrict__ Qout,
                                               const float* __restrict__ cq,
                                               int Ktot) {
    __shared__ unsigned short shmem[(128 + 256) * 64];
    unsigned short (*As)[64] = (unsigned short(*)[64])shmem;
    unsigned short (*Bs)[64] = (unsigned short(*)[64])(shmem + 128 * 64);
    const int b = blockIdx.x;
    const int pairb = b >> 4, jj = b & 15;
    const int sel = jj >> 3, sub = jj & 7;
    const int mb = pairb * 8 + sub;
    if (mb >= MPAD / 128) return;
    const int m0 = mb * 128;

    const unsigned short* A1 = sel ? Qst : Pst;
    const unsigned short* Bt = sel ? B2 : B1;

    const int tid = threadIdx.x;
    const int lane = tid & 63, wid = tid >> 6;
    const int wr = wid >> 2, wc = wid & 3;
    const int lr = lane & 15, lq = lane >> 4;
    const int srow = tid >> 3;
    const int jphys = tid & 7;
    const int jlog = jphys ^ (srow & 7);
    const int scol_g = jlog * 8;
    const int scol_l = jphys * 8;
    const int xorj = (lr & 7);

    f32x4 acc[4][4];
    #pragma unroll
    for (int m = 0; m < 4; ++m)
        #pragma unroll
        for (int n = 0; n < 4; ++n) { f32x4 z = {0.f,0.f,0.f,0.f}; acc[m][n] = z; }

    const int nk = Ktot >> 6;
    for (int kt = 0; kt < nk; ++kt) {
        const int k0 = kt << 6;
        const unsigned short* Ap; int ka;
        if (k0 < 256) { Ap = X; ka = k0; } else { Ap = A1; ka = k0 - 256; }
        #pragma unroll
        for (int p = 0; p < 2; ++p) {
            int row = p * 64 + srow;
            gload_lds16(Ap + (size_t)(m0 + row) * DD + ka + scol_g, &As[row][scol_l]);
        }
        #pragma unroll
        for (int p = 0; p < 4; ++p) {
            int row = p * 64 + srow;
            gload_lds16(Bt + (size_t)row * 512 + k0 + scol_g, &Bs[row][scol_l]);
        }
        __syncthreads();
        #pragma unroll
        for (int h = 0; h < 2; ++h) {
            const int jp = ((h * 4 + lq) ^ xorj) * 8;
            bf16x8 af[4], bfr[4];
            #pragma unroll
            for (int m = 0; m < 4; ++m)
                af[m] = *reinterpret_cast<const bf16x8*>(&As[wr * 64 + m * 16 + lr][jp]);
            #pragma unroll
            for (int n = 0; n < 4; ++n)
                bfr[n] = *reinterpret_cast<const bf16x8*>(&Bs[wc * 64 + n * 16 + lr][jp]);
            #pragma unroll
            for (int m = 0; m < 4; ++m)
                #pragma unroll
                for (int n = 0; n < 4; ++n)
                    acc[m][n] = __builtin_amdgcn_mfma_f32_16x16x32_bf16(af[m], bfr[n], acc[m][n], 0, 0, 0);
        }
        __syncthreads();
    }

    // ---- LDS-staged coalesced epilogue ----
    float cqv[4];
    if (sel) {
        #pragma unroll
        for (int n = 0; n < 4; ++n) cqv[n] = cq[wc * 64 + n * 16 + lr];
    }
    unsigned short* stg = shmem;
    #pragma unroll
    for (int half = 0; half < 2; ++half) {
        if (wr == half) {
            #pragma unroll
            for (int m = 0; m < 4; ++m)
                #pragma unroll
                for (int n = 0; n < 4; ++n) {
                    const int cs = (wc * 64 + n * 16 + lr) ^ (lq << 4);
                    #pragma unroll
                    for (int j = 0; j < 4; ++j) {
                        float v = acc[m][n][j];
                        if (sel) v += cqv[n];
                        stg[(m * 16 + lq * 4 + j) * 256 + cs] = f2bf(v);
                    }
                }
        }
        __syncthreads();
        const int rbase = m0 + half * 64;
        #pragma unroll
        for (int t = 0; t < 4; ++t) {
            int tt = tid + t * 512;
            int rl = tt >> 5, ch = tt & 31;
            int chs = ch ^ (((rl >> 2) & 3) << 1);
            us8 pv = *(const us8*)&stg[rl * 256 + chs * 8];
            size_t gidx = (size_t)(rbase + rl) * 32 + ch;
            if (sel == 0) {
                us8 xv = ((const us8*)X)[gidx];
                us8 o;
                #pragma unroll
                for (int c = 0; c < 8; ++c) o[c] = f2bf(bf2f(pv[c]) + bf2f(xv[c]));
                ((us8*)Pout)[gidx] = pv;
                ((us8*)PXout)[gidx] = o;
            } else {
                ((us8*)Qout)[gidx] = pv;
            }
        }
        __syncthreads();
    }
}

// ---------------- BN GEMM: x = relu((aggB @ nnt^T) * scale + shift), staged epilogue ----------------
__global__ __launch_bounds__(512) void gemm_bn(const unsigned short* __restrict__ A,
                                               const unsigned short* __restrict__ Bt,
                                               unsigned short* __restrict__ Cout,
                                               const float* __restrict__ scale,
                                               const float* __restrict__ shift) {
    __shared__ unsigned short shmem[(128 + 256) * 64];
    unsigned short (*As)[64] = (unsigned short(*)[64])shmem;
    unsigned short (*Bs)[64] = (unsigned short(*)[64])(shmem + 128 * 64);
    const int tid = threadIdx.x;
    const int lane = tid & 63, wid = tid >> 6;
    const int wr = wid >> 2, wc = wid & 3;
    const int m0 = blockIdx.x * 128;
    const int lr = lane & 15, lq = lane >> 4;
    const int srow = tid >> 3;
    const int jphys = tid & 7;
    const int jlog = jphys ^ (srow & 7);
    const int scol_g = jlog * 8;
    const int scol_l = jphys * 8;
    const int xorj = (lr & 7);

    f32x4 acc[4][4];
    #pragma unroll
    for (int m = 0; m < 4; ++m)
        #pragma unroll
        for (int n = 0; n < 4; ++n) { f32x4 z = {0.f,0.f,0.f,0.f}; acc[m][n] = z; }

    for (int kt = 0; kt < 4; ++kt) {
        const int k0 = kt << 6;
        #pragma unroll
        for (int p = 0; p < 2; ++p) {
            int row = p * 64 + srow;
            gload_lds16(A + (size_t)(m0 + row) * DD + k0 + scol_g, &As[row][scol_l]);
        }
        #pragma unroll
        for (int p = 0; p < 4; ++p) {
            int row = p * 64 + srow;
            gload_lds16(Bt + (size_t)row * DD + k0 + scol_g, &Bs[row][scol_l]);
        }
        __syncthreads();
        #pragma unroll
        for (int h = 0; h < 2; ++h) {
            const int jp = ((h * 4 + lq) ^ xorj) * 8;
            bf16x8 af[4], bfr[4];
            #pragma unroll
            for (int m = 0; m < 4; ++m)
                af[m] = *reinterpret_cast<const bf16x8*>(&As[wr * 64 + m * 16 + lr][jp]);
            #pragma unroll
            for (int n = 0; n < 4; ++n)
                bfr[n] = *reinterpret_cast<const bf16x8*>(&Bs[wc * 64 + n * 16 + lr][jp]);
            #pragma unroll
            for (int m = 0; m < 4; ++m)
                #pragma unroll
                for (int n = 0; n < 4; ++n)
                    acc[m][n] = __builtin_amdgcn_mfma_f32_16x16x32_bf16(af[m], bfr[n], acc[m][n], 0, 0, 0);
        }
        __syncthreads();
    }

    float scl[4], shf[4];
    #pragma unroll
    for (int n = 0; n < 4; ++n) {
        int c = wc * 64 + n * 16 + lr;
        scl[n] = scale[c]; shf[n] = shift[c];
    }
    unsigned short* stg = shmem;
    #pragma unroll
    for (int half = 0; half < 2; ++half) {
        if (wr == half) {
            #pragma unroll
            for (int m = 0; m < 4; ++m)
                #pragma unroll
                for (int n = 0; n < 4; ++n) {
                    const int cs = (wc * 64 + n * 16 + lr) ^ (lq << 4);
                    #pragma unroll
                    for (int j = 0; j < 4; ++j) {
                        float y = fmaxf(acc[m][n][j] * scl[n] + shf[n], 0.f);
                        stg[(m * 16 + lq * 4 + j) * 256 + cs] = f2bf(y);
                    }
                }
        }
        __syncthreads();
        const int rbase = m0 + half * 64;
        #pragma unroll
        for (int t = 0; t < 4; ++t) {
            int tt = tid + t * 512;
            int rl = tt >> 5, ch = tt & 31;
            int chs = ch ^ (((rl >> 2) & 3) << 1);
            us8 pv = *(const us8*)&stg[rl * 256 + chs * 8];
            ((us8*)Cout)[(size_t)(rbase + rl) * 32 + ch] = pv;
        }
        __syncthreads();
    }
}

// ---------------- edge pass (CSR gather, single-gather): one wave per node ----------------
// aggB[n] = x[n] + sum_{e: col(e)=n} relu( PX[r] + Qv[n] + w*u )
__global__ __launch_bounds__(256) void edge_csr(const int* __restrict__ offsets, const int* __restrict__ counts,
                                                const int* __restrict__ srow, const float* __restrict__ sw,
                                                const unsigned short* __restrict__ X,
                                                const unsigned short* __restrict__ PX,
                                                const unsigned short* __restrict__ Qv,
                                                const float* __restrict__ u,
                                                unsigned short* __restrict__ aggB) {
    const int lane = threadIdx.x & 63, wid = threadIdx.x >> 6;
    const int n = blockIdx.x * 4 + wid;
    if (n >= NNODE) return;
    const int start = offsets[n];
    const int deg = counts[n];
    const int sub = lane & 31, h = lane >> 5;

    const us8* PX8 = (const us8*)PX;

    float4 u0 = ((const float4*)u)[sub * 2], u1 = ((const float4*)u)[sub * 2 + 1];
    float uu[8] = {u0.x, u0.y, u0.z, u0.w, u1.x, u1.y, u1.z, u1.w};

    us8 qv = ((const us8*)Qv)[(size_t)n * 32 + sub];
    float qb[8];
    #pragma unroll
    for (int c = 0; c < 8; ++c) qb[c] = bf2f(qv[c]);

    float a[8];
    us8 xv = ((const us8*)X)[(size_t)n * 32 + sub];
    #pragma unroll
    for (int c = 0; c < 8; ++c) a[c] = (h == 0) ? bf2f(xv[c]) : 0.f;

    for (int b0 = 0; b0 < deg; b0 += 64) {
        int m = deg - b0; if (m > 64) m = 64;
        int myr = 0; float myw = 0.f;
        if (lane < m) { myr = srow[start + b0 + lane]; myw = sw[start + b0 + lane]; }
        int iters = (m + 1) >> 1;
        for (int j = 0; j < iters; ++j) {
            int el = 2 * j + h;
            int r = __shfl(myr, el);
            float w = __shfl(myw, el);
            if (el < m) {
                us8 p2 = PX8[(size_t)r * 32 + sub];
                #pragma unroll
                for (int c = 0; c < 8; ++c)
                    a[c] += fmaxf(bf2f(p2[c]) + qb[c] + w * uu[c], 0.f);
            }
        }
    }
    #pragma unroll
    for (int c = 0; c < 8; ++c) a[c] += __shfl_xor(a[c], 32);
    if (h == 0) {
        us8 o;
        #pragma unroll
        for (int c = 0; c < 8; ++c) o[c] = f2bf(a[c]);
        ((us8*)aggB)[(size_t)n * 32 + sub] = o;
    }
}

// ---------------- pooling: pooled[batch[n]] += x[n], batch sorted ----------------
__global__ __launch_bounds__(256) void pool_kernel(const unsigned short* __restrict__ x,
                                                   const int* __restrict__ batch,
                                                   float* __restrict__ pooled) {
    const int lane = threadIdx.x & 63, wid = threadIdx.x >> 6;
    const int base = (blockIdx.x * 4 + wid) * 8;
    float4 acc = make_float4(0.f, 0.f, 0.f, 0.f);
    int gcur = -1;
    for (int i = 0; i < 8; ++i) {
        int n = base + i;
        if (n >= NNODE) break;
        int g = batch[n];
        if (g != gcur) {
            if (gcur >= 0) {
                float* pp = pooled + (size_t)gcur * DD + lane * 4;
                unsafeAtomicAdd(pp + 0, acc.x);
                unsafeAtomicAdd(pp + 1, acc.y);
                unsafeAtomicAdd(pp + 2, acc.z);
                unsafeAtomicAdd(pp + 3, acc.w);
            }
            gcur = g;
            acc = make_float4(0.f, 0.f, 0.f, 0.f);
        }
        ushort4 xv = ((const ushort4*)x)[(size_t)n * 64 + lane];
        acc.x += bf2f(xv.x); acc.y += bf2f(xv.y);
        acc.z += bf2f(xv.z); acc.w += bf2f(xv.w);
    }
    if (gcur >= 0) {
        float* pp = pooled + (size_t)gcur * DD + lane * 4;
        unsafeAtomicAdd(pp + 0, acc.x);
        unsafeAtomicAdd(pp + 1, acc.y);
        unsafeAtomicAdd(pp + 2, acc.z);
        unsafeAtomicAdd(pp + 3, acc.w);
    }
}

// ---------------- out: d_out = pooled @ outW + outb ----------------
__global__ __launch_bounds__(64) void out_kernel(const float* __restrict__ pooled,
                                                 const float* __restrict__ outW,
                                                 const float* __restrict__ outb,
                                                 float* __restrict__ out) {
    const int g = blockIdx.x, lane = threadIdx.x;
    float4 p = ((const float4*)pooled)[g * 64 + lane];
    float s[6];
    #pragma unroll
    for (int j = 0; j < 6; ++j) {
        float a = p.x * outW[(lane * 4 + 0) * 6 + j] + p.y * outW[(lane * 4 + 1) * 6 + j] +
                  p.z * outW[(lane * 4 + 2) * 6 + j] + p.w * outW[(lane * 4 + 3) * 6 + j];
        #pragma unroll
        for (int off = 32; off; off >>= 1) a += __shfl_down(a, off);
        s[j] = a;
    }
    if (lane == 0) {
        #pragma unroll
        for (int j = 0; j < 6; ++j) out[g * 6 + j] = s[j] + outb[j];
    }
}

extern "C" void kernel_launch(void* const* d_in, const int* in_sizes, int n_in,
                              void* d_out, int out_size, void* d_ws, size_t ws_size,
                              hipStream_t stream) {
    const float* nf    = (const float*)d_in[0];
    const int*   ei    = (const int*)d_in[1];
    const float* aw    = (const float*)d_in[2];
    const int*   batch = (const int*)d_in[3];
    const float* aW    = (const float*)d_in[4];
    const float* ab    = (const float*)d_in[5];
    const float* eW    = (const float*)d_in[6];
    const float* eb    = (const float*)d_in[7];
    const float* mlpW  = (const float*)d_in[8];
    const float* mlpb  = (const float*)d_in[9];
    const float* nnW   = (const float*)d_in[10];
    const float* nnb   = (const float*)d_in[11];
    const float* bn_g  = (const float*)d_in[12];
    const float* bn_b  = (const float*)d_in[13];
    const float* bn_m  = (const float*)d_in[14];
    const float* bn_v  = (const float*)d_in[15];
    const float* outW  = (const float*)d_in[16];
    const float* outb  = (const float*)d_in[17];
    float* out = (float*)d_out;

    char* ws = (char*)d_ws;
    size_t off = 0;
    auto alloc = [&](size_t bytes) -> void* {
        void* p = ws + off;
        off += (bytes + 255) & ~(size_t)255;
        return p;
    };
    unsigned short* x    = (unsigned short*)alloc((size_t)MPAD * DD * 2);
    unsigned short* P    = (unsigned short*)alloc((size_t)MPAD * DD * 2);
    unsigned short* Qv   = (unsigned short*)alloc((size_t)MPAD * DD * 2);
    unsigned short* aggB = (unsigned short*)alloc((size_t)MPAD * DD * 2);
    // PX shares its region with nfb (nfb dead after xinit; PX written from layer 0 on)
    unsigned short* PX   = (unsigned short*)alloc((size_t)MPAD * DD * 2);
    unsigned short* nfb  = PX;   // MPAD*96*2 < MPAD*DD*2, alias is safe
    unsigned short* wc1  = (unsigned short*)alloc(256 * 512 * 2);
    unsigned short* wc2  = (unsigned short*)alloc(256 * 512 * 2);
    unsigned short* nnt  = (unsigned short*)alloc(256 * 256 * 2);
    unsigned short* aWt  = (unsigned short*)alloc(256 * 96 * 2);
    float* u_all = (float*)alloc(4 * DD * 4);
    float* v_all = (float*)alloc(4 * DD * 4);
    float* scale = (float*)alloc(DD * 4);
    float* shift = (float*)alloc(DD * 4);
    float* pooled = (float*)alloc((size_t)NGRAPH * DD * 4);
    int* counts  = (int*)alloc((size_t)NNODE * 4);
    int* offsets = (int*)alloc((size_t)NNODE * 4);
    int* cursor  = (int*)alloc((size_t)NNODE * 4);
    int* blockSums = (int*)alloc(NCHUNK * 4);
    int* srowB   = (int*)alloc((size_t)NEDGE * 4);
    float* swB   = (float*)alloc((size_t)NEDGE * 4);
    (void)ws_size; (void)in_sizes; (void)n_in; (void)out_size;

    // one-time prep
    prep_weights<<<512, 256, 0, stream>>>(mlpW, nnW, aW, ab, wc1, wc2, nnt, aWt);
    prep_uv<<<1, 256, 0, stream>>>(eW, eb, mlpW, mlpb, nnb, bn_g, bn_b, bn_m, bn_v,
                                   u_all, v_all, scale, shift);
    nfb_prep<<<(MPAD * 96 + 255) / 256, 256, 0, stream>>>(nf, nfb);
    xinit_gemm<<<MPAD / 128, 512, 0, stream>>>(nfb, aWt, x);

    // CSR build (once; shared by all 4 layers)
    hipMemsetAsync(counts, 0, (size_t)NNODE * 4, stream);
    hist_kernel<<<(NEDGE + 255) / 256, 256, 0, stream>>>(ei, counts);
    scan1<<<NCHUNK, 256, 0, stream>>>(counts, blockSums);
    scan2<<<1, 64, 0, stream>>>(blockSums);
    scan3<<<NCHUNK, 256, 0, stream>>>(counts, blockSums, offsets, cursor);
    scatter_kernel<<<(NEDGE + 255) / 256, 256, 0, stream>>>(ei, aw, cursor, srowB, swB);

    const int npairs = (MPAD / 128 + 7) / 8;   // 59
    for (int k = 0; k < 4; ++k) {
        gemm_pq<<<npairs * 16, 512, 0, stream>>>(x, P, Qv, wc1, wc2, P, PX, Qv,
                                                 k == 0 ? v_all : mlpb, k ? 512 : 256);
        edge_csr<<<(NNODE + 3) / 4, 256, 0, stream>>>(offsets, counts, srowB, swB, x, PX, Qv,
                                                      u_all + k * DD, aggB);
        gemm_bn<<<MPAD / 128, 512, 0, stream>>>(aggB, nnt, x, scale, shift);
    }

    hipMemsetAsync(pooled, 0, (size_t)NGRAPH * DD * 4, stream);
    pool_kernel<<<(NNODE + 31) / 32, 256, 0, stream>>>(x, batch, pooled);
    out_kernel<<<NGRAPH, 64, 0, stream>>>(pooled, outW, outb, out);
}